// Round 6
// baseline (495.455 us; speedup 1.0000x reference)
//
#include <hip/hip_runtime.h>
#include <hip/hip_bf16.h>

typedef unsigned short u16;
typedef __attribute__((ext_vector_type(4))) float f32x4;
typedef __attribute__((ext_vector_type(8))) short short8;

#define NB   8
#define CIN  256
#define EDIM 256
#define M3   768
#define HWN  4096
#define LND  64
#define KS2  136   // GEMM LDS row stride (bf16 elems): 272B, 16B aligned

__device__ __forceinline__ float bf2f(u16 u){ return __uint_as_float(((unsigned)u)<<16); }
__device__ __forceinline__ u16 f2bf(float f){ __hip_bfloat16 h = __float2bfloat16(f); return *reinterpret_cast<u16*>(&h); }
__device__ __forceinline__ void bf2x2(unsigned u, float &lo, float &hi){
  lo = __uint_as_float(u<<16);
  hi = __uint_as_float(u & 0xffff0000u);
}

// ---------------- prep: Xt[n][p][c] (bf16) = transpose of X[n][c][p] (fp32) ----------------
__global__ __launch_bounds__(256) void k_prep(const float* __restrict__ x, u16* __restrict__ Xt){
  __shared__ float Ts[64*65];
  const int bi = blockIdx.x;
  const int n = bi>>8, rem = bi&255, ct = rem>>6, pt = rem&63;
  const int c0 = ct*64, p0 = pt*64, tid = threadIdx.x;
  {
    int cc = tid>>2, pj = (tid&3)*16;
    const float* xp = x + (size_t)n*CIN*HWN + (size_t)(c0+cc)*HWN + p0 + pj;
    #pragma unroll
    for(int j=0;j<16;j++) Ts[cc*65 + pj + j] = xp[j];
  }
  __syncthreads();
  {
    int pp = tid>>2, ej = (tid&3)*16;
    u16* op = Xt + ((size_t)n*HWN + p0 + pp)*CIN + c0 + ej;
    ushort4 o[4];
    #pragma unroll
    for(int j=0;j<16;j++) ((u16*)o)[j] = f2bf(Ts[(ej+j)*65 + pp]);
    *(ushort4*)(op+0)  = o[0];
    *(ushort4*)(op+4)  = o[1];
    *(ushort4*)(op+8)  = o[2];
    *(ushort4*)(op+12) = o[3];
  }
}

// ---------------- QKV GEMM 128x128xK256 bf16 MFMA: Y[n][ch][p] = W x X + b ----------------
// grid 1536 linear; n = bi&7 pins each batch's Xt to one XCD's L2.
__global__ __launch_bounds__(256) void k_qkv(const float* __restrict__ w, const u16* __restrict__ Xt,
                                             const float* __restrict__ bias, u16* __restrict__ Y){
  __shared__ u16 As[128*KS2];
  __shared__ u16 Bs[128*KS2];
  const int bi = blockIdx.x;
  const int n = bi&7, rem = bi>>3;
  const int ch0 = (rem%6)*128, p0 = (rem/6)*128;
  const int tid = threadIdx.x;
  const int c = tid&15, qq = (tid>>4)&3, w4 = tid>>6;
  const int wr0 = (w4&1)*64, wc0 = (w4>>1)*64;
  const u16* xb = Xt + ((size_t)n*HWN + p0)*CIN;
  f32x4 acc[4][4];
  #pragma unroll
  for(int mt=0;mt<4;mt++)
    #pragma unroll
    for(int nt=0;nt<4;nt++){ acc[mt][nt][0]=0.f; acc[mt][nt][1]=0.f; acc[mt][nt][2]=0.f; acc[mt][nt][3]=0.f; }
  const int ra = tid&127, ca = tid>>7;
  for(int ph=0; ph<2; ph++){
    { // stage A (fp32 W -> bf16)
      const float* ga = w + (size_t)(ch0+ra)*CIN + ph*128 + ca*64;
      u16* la = &As[ra*KS2 + ca*64];
      #pragma unroll
      for(int j=0;j<8;j++){
        float4 v0 = *(const float4*)(ga + j*8);
        float4 v1 = *(const float4*)(ga + j*8 + 4);
        ushort4 o0, o1;
        o0.x=f2bf(v0.x); o0.y=f2bf(v0.y); o0.z=f2bf(v0.z); o0.w=f2bf(v0.w);
        o1.x=f2bf(v1.x); o1.y=f2bf(v1.y); o1.z=f2bf(v1.z); o1.w=f2bf(v1.w);
        *(ushort4*)(la + j*8)     = o0;
        *(ushort4*)(la + j*8 + 4) = o1;
      }
    }
    { // stage B (bf16 Xt rows, contiguous)
      const u16* gb = xb + (size_t)ra*CIN + ph*128 + ca*64;
      u16* lb = &Bs[ra*KS2 + ca*64];
      #pragma unroll
      for(int j=0;j<8;j++)
        *(short8*)(lb + j*8) = *(const short8*)(gb + j*8);
    }
    __syncthreads();
    #pragma unroll
    for(int kt=0;kt<4;kt++){
      short8 af[4], bf[4];
      #pragma unroll
      for(int mt=0;mt<4;mt++) af[mt] = *(const short8*)&As[(wr0+mt*16+c)*KS2 + kt*32 + qq*8];
      #pragma unroll
      for(int nt=0;nt<4;nt++) bf[nt] = *(const short8*)&Bs[(wc0+nt*16+c)*KS2 + kt*32 + qq*8];
      #pragma unroll
      for(int mt=0;mt<4;mt++)
        #pragma unroll
        for(int nt=0;nt<4;nt++)
          acc[mt][nt] = __builtin_amdgcn_mfma_f32_16x16x32_bf16(af[mt], bf[nt], acc[mt][nt], 0, 0, 0);
    }
    __syncthreads();
  }
  u16* Yb = Y + (size_t)n*M3*HWN;
  #pragma unroll
  for(int mt=0;mt<4;mt++){
    int chb = ch0 + wr0 + mt*16 + 4*qq;
    float b0 = bias[chb], b1 = bias[chb+1], b2 = bias[chb+2], b3 = bias[chb+3];
    #pragma unroll
    for(int nt=0;nt<4;nt++){
      int p = p0 + wc0 + nt*16 + c;
      u16* yp = Yb + (size_t)chb*HWN + p;
      yp[0]           = f2bf(acc[mt][nt][0]+b0);
      yp[HWN]         = f2bf(acc[mt][nt][1]+b1);
      yp[2*(size_t)HWN] = f2bf(acc[mt][nt][2]+b2);
      yp[3*(size_t)HWN] = f2bf(acc[mt][nt][3]+b3);
    }
  }
}

// ---------------- landmarks ----------------
__global__ void k_land(const u16* __restrict__ Y, float* __restrict__ qland, float* __restrict__ kland){
  const int l = blockIdx.x, n = blockIdx.y, e = threadIdx.x;
  const u16* base = Y + (size_t)n*M3*HWN;
  float qs=0.f, ks=0.f;
  #pragma unroll 8
  for(int m=0;m<64;m++){
    size_t off = (size_t)(l*64+m)*M3;
    qs += bf2f(base[off+e]);
    ks += bf2f(base[off+256+e]);
  }
  qland[((size_t)n*LND+l)*EDIM+e] = qs*(1.f/4096.f);
  kland[((size_t)n*LND+l)*EDIM+e] = ks*(1.f/4096.f);
}

// ---------------- Z1[n][j][i] = kland_j · q_i ; Z3[n][i][j] = qland_i · k_j ----------------
__global__ __launch_bounds__(256) void k_landgemm(const u16* __restrict__ Y, const float* __restrict__ qland,
                                                  const float* __restrict__ kland, float* __restrict__ Z1,
                                                  float* __restrict__ Z3){
  const int z = blockIdx.y, n = z>>1, which = z&1;
  const int b0 = blockIdx.x*64;
  const float* land = (which ? qland : kland) + (size_t)n*LND*EDIM;
  const int boff = which ? 256 : 0;
  float* out = (which ? Z3 : Z1) + (size_t)n*LND*HWN;
  const u16* Yb = Y + (size_t)n*M3*HWN;
  __shared__ float Ls[32][68];
  __shared__ float Bs[32][68];
  const int tid = threadIdx.x, tx = tid&15, ty = tid>>4;
  float acc[4][4] = {};
  for(int e0=0;e0<EDIM;e0+=32){
    {
      int a = tid>>2, e8 = (tid&3)*8;
      const float* lp = land + (size_t)a*EDIM + e0 + e8;
      float4 v0 = *(const float4*)lp, v1 = *(const float4*)(lp+4);
      Ls[e8+0][a]=v0.x; Ls[e8+1][a]=v0.y; Ls[e8+2][a]=v0.z; Ls[e8+3][a]=v0.w;
      Ls[e8+4][a]=v1.x; Ls[e8+5][a]=v1.y; Ls[e8+6][a]=v1.z; Ls[e8+7][a]=v1.w;
      const u16* bp = Yb + (size_t)(b0+a)*M3 + boff + e0 + e8;
      ushort4 u0 = *(const ushort4*)bp, u1 = *(const ushort4*)(bp+4);
      Bs[e8+0][a]=bf2f(u0.x); Bs[e8+1][a]=bf2f(u0.y); Bs[e8+2][a]=bf2f(u0.z); Bs[e8+3][a]=bf2f(u0.w);
      Bs[e8+4][a]=bf2f(u1.x); Bs[e8+5][a]=bf2f(u1.y); Bs[e8+6][a]=bf2f(u1.z); Bs[e8+7][a]=bf2f(u1.w);
    }
    __syncthreads();
    #pragma unroll
    for(int e=0;e<32;e++){
      f32x4 a = *(f32x4*)&Ls[e][ty*4];
      f32x4 b = *(f32x4*)&Bs[e][tx*4];
      #pragma unroll
      for(int s=0;s<4;s++)
        #pragma unroll
        for(int u=0;u<4;u++) acc[s][u] += a[s]*b[u];
    }
    __syncthreads();
  }
  #pragma unroll
  for(int s=0;s<4;s++){
    float4 fv = make_float4(acc[s][0],acc[s][1],acc[s][2],acc[s][3]);
    *(float4*)&out[(size_t)(ty*4+s)*HWN + b0 + tx*4] = fv;
  }
}

// ---------------- softmax of Z1 over contiguous 4096 ----------------
__global__ void k_soft1(float* __restrict__ Z1){
  const int b = blockIdx.x, n = b>>6, j = b&63, tid = threadIdx.x;
  float* base = Z1 + ((size_t)n*LND + j)*HWN;
  float v[16];
  float m = -1e30f;
  #pragma unroll
  for(int r=0;r<16;r++){ v[r] = base[r*256 + tid]; m = fmaxf(m, v[r]); }
  #pragma unroll
  for(int o=32;o;o>>=1) m = fmaxf(m, __shfl_xor(m, o));
  __shared__ float redm[4], reds[4];
  const int wid = tid>>6;
  if((tid&63)==0) redm[wid] = m;
  __syncthreads();
  m = fmaxf(fmaxf(redm[0],redm[1]), fmaxf(redm[2],redm[3]));
  float s = 0.f;
  #pragma unroll
  for(int r=0;r<16;r++){ v[r] = __expf(v[r]-m); s += v[r]; }
  #pragma unroll
  for(int o=32;o;o>>=1) s += __shfl_xor(s, o);
  if((tid&63)==0) reds[wid] = s;
  __syncthreads();
  s = reds[0]+reds[1]+reds[2]+reds[3];
  float inv = 1.f/s;
  #pragma unroll
  for(int r=0;r<16;r++) base[r*256 + tid] = v[r]*inv;
}

// ---------------- softmax of Z3 over the 64-landmark (strided) dim ----------------
__global__ void k_soft3(float* __restrict__ Z3){
  const int n = blockIdx.y;
  const int j = blockIdx.x*256 + threadIdx.x;
  float* base = Z3 + (size_t)n*LND*HWN + j;
  float v[64];
  float m = -1e30f;
  #pragma unroll
  for(int i=0;i<64;i++){ v[i] = base[(size_t)i*HWN]; m = fmaxf(m, v[i]); }
  float s = 0.f;
  #pragma unroll
  for(int i=0;i<64;i++){ v[i] = __expf(v[i]-m); s += v[i]; }
  float inv = 1.f/s;
  #pragma unroll
  for(int i=0;i<64;i++) base[(size_t)i*HWN] = v[i]*inv;
}

// ---------------- fp32 VALU 64x64 matmul helper ----------------
__device__ __forceinline__ void mm64(const float* A, const float* B, int i0, int j0, float r[4][4]){
  #pragma unroll
  for(int s=0;s<4;s++)
    #pragma unroll
    for(int u=0;u<4;u++) r[s][u] = 0.f;
  for(int l0=0;l0<64;l0+=4){
    f32x4 a0 = *(const f32x4*)&A[(i0+0)*64+l0];
    f32x4 a1 = *(const f32x4*)&A[(i0+1)*64+l0];
    f32x4 a2 = *(const f32x4*)&A[(i0+2)*64+l0];
    f32x4 a3 = *(const f32x4*)&A[(i0+3)*64+l0];
    #pragma unroll
    for(int t=0;t<4;t++){
      f32x4 b = *(const f32x4*)&B[(l0+t)*64+j0];
      #pragma unroll
      for(int u=0;u<4;u++){
        r[0][u] += a0[t]*b[u];
        r[1][u] += a1[t]*b[u];
        r[2][u] += a2[t]*b[u];
        r[3][u] += a3[t]*b[u];
      }
    }
  }
}

// ---------------- k2 + Newton-Schulz, fp32 ----------------
__global__ __launch_bounds__(256) void k_ns(const float* __restrict__ qland, const float* __restrict__ kland,
                                            float* __restrict__ KinvT){
  __shared__ float Km[64*64];
  __shared__ float Vm[64*64];
  __shared__ float Am[64*64];
  __shared__ float Bm[64*64];
  float* sred = Am;
  const int tid = threadIdx.x, n = blockIdx.x;
  const float* qb = qland + (size_t)n*LND*EDIM;
  const float* kb = kland + (size_t)n*LND*EDIM;
  const int i0 = (tid>>4)*4, j0 = (tid&15)*4;
  float r[4][4];
  #pragma unroll
  for(int s=0;s<4;s++)
    #pragma unroll
    for(int u=0;u<4;u++) r[s][u] = 0.f;
  for(int e0=0;e0<EDIM;e0+=64){
    __syncthreads();
    {
      int a = tid>>2, e16 = (tid&3)*16;
      #pragma unroll
      for(int t=0;t<16;t+=4){
        float4 qv = *(const float4*)(qb + (size_t)a*EDIM + e0 + e16 + t);
        float4 kv = *(const float4*)(kb + (size_t)a*EDIM + e0 + e16 + t);
        Am[(e16+t+0)*64+a]=qv.x; Am[(e16+t+1)*64+a]=qv.y; Am[(e16+t+2)*64+a]=qv.z; Am[(e16+t+3)*64+a]=qv.w;
        Bm[(e16+t+0)*64+a]=kv.x; Bm[(e16+t+1)*64+a]=kv.y; Bm[(e16+t+2)*64+a]=kv.z; Bm[(e16+t+3)*64+a]=kv.w;
      }
    }
    __syncthreads();
    for(int e=0;e<64;e++){
      f32x4 a = *(f32x4*)&Am[e*64+i0];
      f32x4 b = *(f32x4*)&Bm[e*64+j0];
      #pragma unroll
      for(int s=0;s<4;s++)
        #pragma unroll
        for(int u=0;u<4;u++) r[s][u] += a[s]*b[u];
    }
  }
  __syncthreads();
  #pragma unroll
  for(int s=0;s<4;s++){
    f32x4 v = {r[s][0], r[s][1], r[s][2], r[s][3]};
    *(f32x4*)&Km[(i0+s)*64 + j0] = v;
  }
  __syncthreads();
  if(tid < 64){
    int j = tid;
    float m = -1e30f;
    for(int i=0;i<64;i++) m = fmaxf(m, Km[i*64+j]);
    float ssum = 0.f;
    for(int i=0;i<64;i++) ssum += __expf(Km[i*64+j]-m);
    float inv = 1.f/ssum, cs = 0.f;
    for(int i=0;i<64;i++){
      float kv = __expf(Km[i*64+j]-m)*inv;
      Km[i*64+j] = kv;
      cs += fabsf(kv);
    }
    sred[j] = cs;
  }
  __syncthreads();
  if(tid < 64){
    int i = tid; float rs = 0.f;
    for(int j=0;j<64;j++) rs += fabsf(Km[i*64+j]);
    sred[64+i] = rs;
  }
  __syncthreads();
  if(tid == 0){
    float v0=-1e30f, vi=-1e30f;
    for(int t=0;t<64;t++){ v0 = fmaxf(v0, sred[t]); vi = fmaxf(vi, sred[64+t]); }
    sred[128] = 1.f/(v0*vi);
  }
  __syncthreads();
  {
    float sc = sred[128];
    #pragma unroll
    for(int s=0;s<4;s++)
      #pragma unroll
      for(int u=0;u<4;u++) Vm[(i0+s)*64 + j0+u] = Km[(j0+u)*64 + i0+s]*sc;
  }
  __syncthreads();
  for(int it=0; it<6; it++){
    mm64(Km, Vm, i0, j0, r);
    #pragma unroll
    for(int s=0;s<4;s++){
      f32x4 v = {r[s][0], r[s][1], r[s][2], r[s][3]};
      *(f32x4*)&Am[(i0+s)*64 + j0] = v;
    }
    __syncthreads();
    mm64(Am, Am, i0, j0, r);
    #pragma unroll
    for(int s=0;s<4;s++)
      #pragma unroll
      for(int u=0;u<4;u++) Bm[(i0+s)*64+j0+u] = 7.f*Am[(i0+s)*64+j0+u] - r[s][u];
    __syncthreads();
    mm64(Am, Bm, i0, j0, r);
    __syncthreads();
    #pragma unroll
    for(int s=0;s<4;s++)
      #pragma unroll
      for(int u=0;u<4;u++) Bm[(i0+s)*64+j0+u] = 15.f*Am[(i0+s)*64+j0+u] - r[s][u];
    __syncthreads();
    mm64(Vm, Bm, i0, j0, r);
    __syncthreads();
    #pragma unroll
    for(int s=0;s<4;s++)
      #pragma unroll
      for(int u=0;u<4;u++) Vm[(i0+s)*64+j0+u] = 0.25f*(13.f*Vm[(i0+s)*64+j0+u] - r[s][u]);
    __syncthreads();
  }
  #pragma unroll
  for(int u=0;u<4;u++){
    int col = j0+u;
    f32x4 fo = { Vm[(i0+0)*64+col], Vm[(i0+1)*64+col], Vm[(i0+2)*64+col], Vm[(i0+3)*64+col] };
    *(f32x4*)&KinvT[(size_t)n*4096 + (size_t)col*64 + i0] = fo;
  }
}

// ---------------- partial k3@v: part[n][kc][64][256] ----------------
#define NSTR 72
__global__ __launch_bounds__(256) void k_f(const float* __restrict__ Z3, const u16* __restrict__ Y,
                                           float* __restrict__ part){
  const int kc = blockIdx.x, n = blockIdx.y, tid = threadIdx.x;
  const int jb = kc*128;
  __shared__ u16 k3T[128*NSTR];
  const float* z3b = Z3 + (size_t)n*LND*HWN;
  {
    int ibase = (tid>>5)*8, j4 = (tid&31)*4;
    #pragma unroll
    for(int r=0;r<8;r++){
      int i = ibase + r;
      float4 v = *(const float4*)&z3b[(size_t)i*HWN + jb + j4];
      k3T[(j4+0)*NSTR + i] = f2bf(v.x);
      k3T[(j4+1)*NSTR + i] = f2bf(v.y);
      k3T[(j4+2)*NSTR + i] = f2bf(v.z);
      k3T[(j4+3)*NSTR + i] = f2bf(v.w);
    }
  }
  __syncthreads();
  const int i0 = (tid>>4)*4, e0 = (tid&15)*16;
  const u16* Yb = Y + (size_t)n*M3*HWN;
  float acc[4][16] = {};
  for(int j=0;j<128;j++){
    ushort4 av = *(const ushort4*)&k3T[(size_t)j*NSTR + i0];
    float a0 = bf2f(av.x), a1 = bf2f(av.y), a2 = bf2f(av.z), a3 = bf2f(av.w);
    const u16* vp = Yb + (size_t)(jb+j)*M3 + 512 + e0;
    uint4 U0 = *(const uint4*)vp;
    uint4 U1 = *(const uint4*)(vp+8);
    float bv[16];
    bf2x2(U0.x, bv[0], bv[1]);  bf2x2(U0.y, bv[2], bv[3]);
    bf2x2(U0.z, bv[4], bv[5]);  bf2x2(U0.w, bv[6], bv[7]);
    bf2x2(U1.x, bv[8], bv[9]);  bf2x2(U1.y, bv[10], bv[11]);
    bf2x2(U1.z, bv[12], bv[13]); bf2x2(U1.w, bv[14], bv[15]);
    #pragma unroll
    for(int u=0;u<16;u++){
      acc[0][u] += a0*bv[u];
      acc[1][u] += a1*bv[u];
      acc[2][u] += a2*bv[u];
      acc[3][u] += a3*bv[u];
    }
  }
  float* pb = part + ((size_t)n*32 + kc)*LND*EDIM;
  #pragma unroll
  for(int s=0;s<4;s++)
    #pragma unroll
    for(int t=0;t<16;t+=4){
      float4 fv = make_float4(acc[s][t],acc[s][t+1],acc[s][t+2],acc[s][t+3]);
      *(float4*)&pb[(size_t)(i0+s)*EDIM + e0 + t] = fv;
    }
}

__global__ void k_fred(const float* __restrict__ part, float* __restrict__ B3){
  const int idx = blockIdx.x*256 + threadIdx.x;
  const int n = idx >> 14, rem = idx & 16383;
  const float* p = part + (size_t)n*32*16384 + rem;
  float s = 0.f;
  #pragma unroll
  for(int kc=0;kc<32;kc++) s += p[(size_t)kc*16384];
  B3[idx] = s;
}

// ---------------- C2[j][e] = sum_l Kinv[j][l]*B3[l][e] ----------------
__global__ __launch_bounds__(256) void k_c2(const float* __restrict__ KinvT, const float* __restrict__ B3,
                                            float* __restrict__ C2){
  const int eb = blockIdx.x*64, n = blockIdx.y, tid = threadIdx.x;
  __shared__ float KT[64][68];
  __shared__ float Bs2[64][68];
  {
    int l = tid>>2, o16 = (tid&3)*16;
    const float* kp = KinvT + (size_t)n*4096 + l*64 + o16;
    const float* bp = B3 + ((size_t)n*LND + l)*EDIM + eb + o16;
    #pragma unroll
    for(int t=0;t<16;t+=4){
      *(float4*)&KT[l][o16+t]  = *(const float4*)(kp+t);
      *(float4*)&Bs2[l][o16+t] = *(const float4*)(bp+t);
    }
  }
  __syncthreads();
  const int j0 = (tid>>4)*4, u0 = (tid&15)*4;
  float acc[4][4] = {};
  #pragma unroll 8
  for(int l=0;l<64;l++){
    f32x4 a = *(f32x4*)&KT[l][j0];
    f32x4 b = *(f32x4*)&Bs2[l][u0];
    #pragma unroll
    for(int s=0;s<4;s++)
      #pragma unroll
      for(int u=0;u<4;u++) acc[s][u] += a[s]*b[u];
  }
  #pragma unroll
  for(int s=0;s<4;s++){
    float4 fv = make_float4(acc[s][0],acc[s][1],acc[s][2],acc[s][3]);
    *(float4*)&C2[((size_t)n*LND + j0+s)*EDIM + eb + u0] = fv;
  }
}

// ---------------- out[i][e] = sum_j k1t[j][i]*C2[j][e] + v[i][e]; OM bf16 [p][e] ----------------
__global__ __launch_bounds__(256) void k_out(const float* __restrict__ Z1, const float* __restrict__ C2,
                                             const u16* __restrict__ Y, u16* __restrict__ OM){
  const int ib = blockIdx.x*64, n = blockIdx.y, tid = threadIdx.x;
  __shared__ float K1s[64][68];
  __shared__ u16 C2s[64*264];
  {
    int j = tid>>2, i16 = (tid&3)*16;
    const float* zp = Z1 + ((size_t)n*LND + j)*HWN + ib + i16;
    #pragma unroll
    for(int t=0;t<16;t+=4) *(float4*)&K1s[j][i16+t] = *(const float4*)(zp+t);
    int e64 = (tid&3)*64;
    const float* cp = C2 + ((size_t)n*LND + j)*EDIM + e64;
    #pragma unroll
    for(int t=0;t<64;t+=4){
      float4 v = *(const float4*)(cp+t);
      C2s[j*264 + e64+t+0] = f2bf(v.x);
      C2s[j*264 + e64+t+1] = f2bf(v.y);
      C2s[j*264 + e64+t+2] = f2bf(v.z);
      C2s[j*264 + e64+t+3] = f2bf(v.w);
    }
  }
  __syncthreads();
  const int i0 = (tid>>4)*4, e0 = (tid&15)*16;
  float acc[4][16] = {};
  for(int j=0;j<64;j++){
    f32x4 a = *(f32x4*)&K1s[j][i0];
    const u16* cb = &C2s[j*264 + e0];
    uint4 U0 = *(const uint4*)cb;
    uint4 U1 = *(const uint4*)(cb+8);
    float bv[16];
    bf2x2(U0.x, bv[0], bv[1]);  bf2x2(U0.y, bv[2], bv[3]);
    bf2x2(U0.z, bv[4], bv[5]);  bf2x2(U0.w, bv[6], bv[7]);
    bf2x2(U1.x, bv[8], bv[9]);  bf2x2(U1.y, bv[10], bv[11]);
    bf2x2(U1.z, bv[12], bv[13]); bf2x2(U1.w, bv[14], bv[15]);
    #pragma unroll
    for(int u=0;u<16;u++){
      acc[0][u] += a[0]*bv[u];
      acc[1][u] += a[1]*bv[u];
      acc[2][u] += a[2]*bv[u];
      acc[3][u] += a[3]*bv[u];
    }
  }
  const u16* Yb = Y + (size_t)n*M3*HWN;
  u16* ob = OM + (size_t)n*HWN*EDIM;
  #pragma unroll
  for(int s=0;s<4;s++){
    int i = ib + i0 + s;
    const u16* vp = Yb + (size_t)i*M3 + 512 + e0;
    uint4 U0 = *(const uint4*)vp, U1 = *(const uint4*)(vp+8);
    float vv[16];
    bf2x2(U0.x, vv[0], vv[1]);  bf2x2(U0.y, vv[2], vv[3]);
    bf2x2(U0.z, vv[4], vv[5]);  bf2x2(U0.w, vv[6], vv[7]);
    bf2x2(U1.x, vv[8], vv[9]);  bf2x2(U1.y, vv[10], vv[11]);
    bf2x2(U1.z, vv[12], vv[13]); bf2x2(U1.w, vv[14], vv[15]);
    #pragma unroll
    for(int t=0;t<16;t+=4){
      ushort4 o;
      o.x = f2bf(acc[s][t+0]+vv[t+0]);
      o.y = f2bf(acc[s][t+1]+vv[t+1]);
      o.z = f2bf(acc[s][t+2]+vv[t+2]);
      o.w = f2bf(acc[s][t+3]+vv[t+3]);
      *(ushort4*)&ob[(size_t)i*EDIM + e0 + t] = o;
    }
  }
}

// ---------------- transpose of raw-reshaped OM: OMT[p''][e'] = OMflat[e'*4096 + p''] ----------------
__global__ __launch_bounds__(256) void k_trans2(const u16* __restrict__ OM, u16* __restrict__ OMT){
  __shared__ u16 Ts[64*65];
  const int bi = blockIdx.x;
  const int n = bi>>8, rem = bi&255, et = rem>>6, pt = rem&63;
  const int e0 = et*64, p0 = pt*64, tid = threadIdx.x;
  const u16* omb = OM + (size_t)n*HWN*EDIM;   // viewed flat: M1[e][p] = flat[e*4096+p]
  {
    int ee = tid>>2, pj = (tid&3)*16;
    const u16* ip = omb + (size_t)(e0+ee)*HWN + p0 + pj;
    ushort4 v0 = *(const ushort4*)(ip);
    ushort4 v1 = *(const ushort4*)(ip+4);
    ushort4 v2 = *(const ushort4*)(ip+8);
    ushort4 v3 = *(const ushort4*)(ip+12);
    u16* tp = &Ts[ee*65 + pj];
    tp[0]=v0.x; tp[1]=v0.y; tp[2]=v0.z; tp[3]=v0.w;
    tp[4]=v1.x; tp[5]=v1.y; tp[6]=v1.z; tp[7]=v1.w;
    tp[8]=v2.x; tp[9]=v2.y; tp[10]=v2.z; tp[11]=v2.w;
    tp[12]=v3.x; tp[13]=v3.y; tp[14]=v3.z; tp[15]=v3.w;
  }
  __syncthreads();
  {
    int pp = tid>>2, ej = (tid&3)*16;
    u16* op = OMT + ((size_t)n*HWN + p0 + pp)*EDIM + e0 + ej;
    ushort4 o[4];
    #pragma unroll
    for(int j=0;j<16;j++) ((u16*)o)[j] = Ts[(ej+j)*65 + pp];
    *(ushort4*)(op+0)  = o[0];
    *(ushort4*)(op+4)  = o[1];
    *(ushort4*)(op+8)  = o[2];
    *(ushort4*)(op+12) = o[3];
  }
}

// ---------------- proj GEMM 128x128xK256: out[n][co][p''] = Wout x M1 + b (fp32 out) ----------------
__global__ __launch_bounds__(256) void k_proj(const float* __restrict__ w, const u16* __restrict__ OMT,
                                              const float* __restrict__ bias, float* __restrict__ out){
  __shared__ u16 As[128*KS2];
  __shared__ u16 Bs[128*KS2];
  const int bi = blockIdx.x;
  const int n = bi&7, rem = bi>>3;
  const int ch0 = (rem&1)*128, p0 = (rem>>1)*128;
  const int tid = threadIdx.x;
  const int c = tid&15, qq = (tid>>4)&3, w4 = tid>>6;
  const int wr0 = (w4&1)*64, wc0 = (w4>>1)*64;
  const u16* xb = OMT + ((size_t)n*HWN + p0)*EDIM;
  f32x4 acc[4][4];
  #pragma unroll
  for(int mt=0;mt<4;mt++)
    #pragma unroll
    for(int nt=0;nt<4;nt++){ acc[mt][nt][0]=0.f; acc[mt][nt][1]=0.f; acc[mt][nt][2]=0.f; acc[mt][nt][3]=0.f; }
  const int ra = tid&127, ca = tid>>7;
  for(int ph=0; ph<2; ph++){
    {
      const float* ga = w + (size_t)(ch0+ra)*EDIM + ph*128 + ca*64;
      u16* la = &As[ra*KS2 + ca*64];
      #pragma unroll
      for(int j=0;j<8;j++){
        float4 v0 = *(const float4*)(ga + j*8);
        float4 v1 = *(const float4*)(ga + j*8 + 4);
        ushort4 o0, o1;
        o0.x=f2bf(v0.x); o0.y=f2bf(v0.y); o0.z=f2bf(v0.z); o0.w=f2bf(v0.w);
        o1.x=f2bf(v1.x); o1.y=f2bf(v1.y); o1.z=f2bf(v1.z); o1.w=f2bf(v1.w);
        *(ushort4*)(la + j*8)     = o0;
        *(ushort4*)(la + j*8 + 4) = o1;
      }
    }
    {
      const u16* gb = xb + (size_t)ra*EDIM + ph*128 + ca*64;
      u16* lb = &Bs[ra*KS2 + ca*64];
      #pragma unroll
      for(int j=0;j<8;j++)
        *(short8*)(lb + j*8) = *(const short8*)(gb + j*8);
    }
    __syncthreads();
    #pragma unroll
    for(int kt=0;kt<4;kt++){
      short8 af[4], bf[4];
      #pragma unroll
      for(int mt=0;mt<4;mt++) af[mt] = *(const short8*)&As[(wr0+mt*16+c)*KS2 + kt*32 + qq*8];
      #pragma unroll
      for(int nt=0;nt<4;nt++) bf[nt] = *(const short8*)&Bs[(wc0+nt*16+c)*KS2 + kt*32 + qq*8];
      #pragma unroll
      for(int mt=0;mt<4;mt++)
        #pragma unroll
        for(int nt=0;nt<4;nt++)
          acc[mt][nt] = __builtin_amdgcn_mfma_f32_16x16x32_bf16(af[mt], bf[nt], acc[mt][nt], 0, 0, 0);
    }
    __syncthreads();
  }
  float* ob = out + (size_t)n*EDIM*HWN;
  #pragma unroll
  for(int mt=0;mt<4;mt++){
    int chb = ch0 + wr0 + mt*16 + 4*qq;
    float b0 = bias[chb], b1 = bias[chb+1], b2 = bias[chb+2], b3 = bias[chb+3];
    #pragma unroll
    for(int nt=0;nt<4;nt++){
      int p = p0 + wc0 + nt*16 + c;
      float* yp = ob + (size_t)chb*HWN + p;
      yp[0]             = acc[mt][nt][0]+b0;
      yp[HWN]           = acc[mt][nt][1]+b1;
      yp[2*(size_t)HWN] = acc[mt][nt][2]+b2;
      yp[3*(size_t)HWN] = acc[mt][nt][3]+b3;
    }
  }
}

extern "C" void kernel_launch(void* const* d_in, const int* in_sizes, int n_in,
                              void* d_out, int out_size, void* d_ws, size_t ws_size,
                              hipStream_t stream){
  (void)out_size; (void)ws_size;
  const float* x     = (const float*)d_in[0];
  const float* w_qkv = (const float*)d_in[1];
  const float* b_qkv = (const float*)d_in[2];
  const float* w_out = (const float*)d_in[3];
  const float* b_out = (const float*)d_in[4];
  for(int i=0;i<n_in;i++){
    switch(in_sizes[i]){
      case 8388608: x     = (const float*)d_in[i]; break;
      case 196608:  w_qkv = (const float*)d_in[i]; break;
      case 768:     b_qkv = (const float*)d_in[i]; break;
      case 65536:   w_out = (const float*)d_in[i]; break;
      case 256:     b_out = (const float*)d_in[i]; break;
      default: break;
    }
  }
  float* out = (float*)d_out;
  char* ws = (char*)d_ws;

  u16*   Y     = (u16*)(ws + 0);              // 50,331,648 B  bf16 [8][768*4096]
  float* qland = (float*)(ws + 50331648);     //    524,288 B
  float* kland = (float*)(ws + 50855936);     //    524,288 B
  float* Z1    = (float*)(ws + 51380224);     //  8,388,608 B
  float* Z3    = (float*)(ws + 59768832);     //  8,388,608 B
  float* KinvT = (float*)(ws + 68157440);     //    131,072 B
  // 16 MB region triple-used sequentially: Xt (k_prep..k_qkv) -> part (k_f..k_fred) -> OMT (k_trans2..k_proj)
  u16*   Xt    = (u16*)(ws + 68288512);       // 16,777,216 B  bf16 [8][4096][256]
  float* part  = (float*)(ws + 68288512);
  u16*   OMT   = (u16*)(ws + 68288512);
  float* B3    = (float*)(ws + 85065728);     //    524,288 B
  float* C2    = (float*)(ws + 85590016);     //    524,288 B
  u16*   OM    = (u16*)(ws + 86114304);       // 16,777,216 B  bf16 [8][4096*256]

  k_prep    <<<dim3(2048),  256, 0, stream>>>(x, Xt);
  k_qkv     <<<dim3(1536),  256, 0, stream>>>(w_qkv, Xt, b_qkv, Y);
  k_land    <<<dim3(64,8),  256, 0, stream>>>(Y, qland, kland);
  k_landgemm<<<dim3(64,16), 256, 0, stream>>>(Y, qland, kland, Z1, Z3);
  k_soft1   <<<dim3(512),   256, 0, stream>>>(Z1);
  k_soft3   <<<dim3(16,8),  256, 0, stream>>>(Z3);
  k_ns      <<<dim3(8),     256, 0, stream>>>(qland, kland, KinvT);
  k_f       <<<dim3(32,8),  256, 0, stream>>>(Z3, Y, part);
  k_fred    <<<dim3(512),   256, 0, stream>>>(part, B3);
  k_c2      <<<dim3(4,8),   256, 0, stream>>>(KinvT, B3, C2);
  k_out     <<<dim3(64,8),  256, 0, stream>>>(Z1, C2, Y, OM);
  k_trans2  <<<dim3(2048),  256, 0, stream>>>(OM, OMT);
  k_proj    <<<dim3(512),   256, 0, stream>>>(w_out, OMT, b_out, out);
}

// Round 7
// 332.519 us; speedup vs baseline: 1.4900x; 1.4900x over previous
//
#include <hip/hip_runtime.h>
#include <hip/hip_bf16.h>

typedef unsigned short u16;
typedef __attribute__((ext_vector_type(4))) float f32x4;
typedef __attribute__((ext_vector_type(8))) short short8;

#define NB   8
#define CIN  256
#define EDIM 256
#define M3   768
#define HWN  4096
#define LND  64
#define KS2  136   // GEMM LDS row stride (bf16 elems): 272B, 16B aligned
#define NS2  72    // NS LDS row stride (bf16 elems): 144B, 16B aligned, 2-way-bank (free)

__device__ __forceinline__ float bf2f(u16 u){ return __uint_as_float(((unsigned)u)<<16); }
__device__ __forceinline__ u16 f2bf(float f){ __hip_bfloat16 h = __float2bfloat16(f); return *reinterpret_cast<u16*>(&h); }
__device__ __forceinline__ void bf2x2(unsigned u, float &lo, float &hi){
  lo = __uint_as_float(u<<16);
  hi = __uint_as_float(u & 0xffff0000u);
}

// ---------------- prep: Xt[n][p][c] (bf16) = transpose of X[n][c][p] (fp32) ----------------
__global__ __launch_bounds__(256) void k_prep(const float* __restrict__ x, u16* __restrict__ Xt){
  __shared__ float Ts[64*65];
  const int bi = blockIdx.x;
  const int n = bi>>8, rem = bi&255, ct = rem>>6, pt = rem&63;
  const int c0 = ct*64, p0 = pt*64, tid = threadIdx.x;
  {
    int cc = tid>>2, pj = (tid&3)*16;
    const float* xp = x + (size_t)n*CIN*HWN + (size_t)(c0+cc)*HWN + p0 + pj;
    #pragma unroll
    for(int j=0;j<16;j++) Ts[cc*65 + pj + j] = xp[j];
  }
  __syncthreads();
  {
    int pp = tid>>2, ej = (tid&3)*16;
    u16* op = Xt + ((size_t)n*HWN + p0 + pp)*CIN + c0 + ej;
    ushort4 o[4];
    #pragma unroll
    for(int j=0;j<16;j++) ((u16*)o)[j] = f2bf(Ts[(ej+j)*65 + pp]);
    *(ushort4*)(op+0)  = o[0];
    *(ushort4*)(op+4)  = o[1];
    *(ushort4*)(op+8)  = o[2];
    *(ushort4*)(op+12) = o[3];
  }
}

// ---------------- QKV GEMM 128x128xK256 bf16 MFMA ----------------
__global__ __launch_bounds__(256) void k_qkv(const float* __restrict__ w, const u16* __restrict__ Xt,
                                             const float* __restrict__ bias, u16* __restrict__ Y){
  __shared__ u16 As[128*KS2];
  __shared__ u16 Bs[128*KS2];
  const int bi = blockIdx.x;
  const int n = bi&7, rem = bi>>3;
  const int ch0 = (rem%6)*128, p0 = (rem/6)*128;
  const int tid = threadIdx.x;
  const int c = tid&15, qq = (tid>>4)&3, w4 = tid>>6;
  const int wr0 = (w4&1)*64, wc0 = (w4>>1)*64;
  const u16* xb = Xt + ((size_t)n*HWN + p0)*CIN;
  f32x4 acc[4][4];
  #pragma unroll
  for(int mt=0;mt<4;mt++)
    #pragma unroll
    for(int nt=0;nt<4;nt++){ acc[mt][nt][0]=0.f; acc[mt][nt][1]=0.f; acc[mt][nt][2]=0.f; acc[mt][nt][3]=0.f; }
  const int ra = tid&127, ca = tid>>7;
  for(int ph=0; ph<2; ph++){
    {
      const float* ga = w + (size_t)(ch0+ra)*CIN + ph*128 + ca*64;
      u16* la = &As[ra*KS2 + ca*64];
      #pragma unroll
      for(int j=0;j<8;j++){
        float4 v0 = *(const float4*)(ga + j*8);
        float4 v1 = *(const float4*)(ga + j*8 + 4);
        ushort4 o0, o1;
        o0.x=f2bf(v0.x); o0.y=f2bf(v0.y); o0.z=f2bf(v0.z); o0.w=f2bf(v0.w);
        o1.x=f2bf(v1.x); o1.y=f2bf(v1.y); o1.z=f2bf(v1.z); o1.w=f2bf(v1.w);
        *(ushort4*)(la + j*8)     = o0;
        *(ushort4*)(la + j*8 + 4) = o1;
      }
    }
    {
      const u16* gb = xb + (size_t)ra*CIN + ph*128 + ca*64;
      u16* lb = &Bs[ra*KS2 + ca*64];
      #pragma unroll
      for(int j=0;j<8;j++)
        *(short8*)(lb + j*8) = *(const short8*)(gb + j*8);
    }
    __syncthreads();
    #pragma unroll
    for(int kt=0;kt<4;kt++){
      short8 af[4], bf[4];
      #pragma unroll
      for(int mt=0;mt<4;mt++) af[mt] = *(const short8*)&As[(wr0+mt*16+c)*KS2 + kt*32 + qq*8];
      #pragma unroll
      for(int nt=0;nt<4;nt++) bf[nt] = *(const short8*)&Bs[(wc0+nt*16+c)*KS2 + kt*32 + qq*8];
      #pragma unroll
      for(int mt=0;mt<4;mt++)
        #pragma unroll
        for(int nt=0;nt<4;nt++)
          acc[mt][nt] = __builtin_amdgcn_mfma_f32_16x16x32_bf16(af[mt], bf[nt], acc[mt][nt], 0, 0, 0);
    }
    __syncthreads();
  }
  u16* Yb = Y + (size_t)n*M3*HWN;
  #pragma unroll
  for(int mt=0;mt<4;mt++){
    int chb = ch0 + wr0 + mt*16 + 4*qq;
    float b0 = bias[chb], b1 = bias[chb+1], b2 = bias[chb+2], b3 = bias[chb+3];
    #pragma unroll
    for(int nt=0;nt<4;nt++){
      int p = p0 + wc0 + nt*16 + c;
      u16* yp = Yb + (size_t)chb*HWN + p;
      yp[0]             = f2bf(acc[mt][nt][0]+b0);
      yp[HWN]           = f2bf(acc[mt][nt][1]+b1);
      yp[2*(size_t)HWN] = f2bf(acc[mt][nt][2]+b2);
      yp[3*(size_t)HWN] = f2bf(acc[mt][nt][3]+b3);
    }
  }
}

// ---------------- landmarks ----------------
__global__ void k_land(const u16* __restrict__ Y, float* __restrict__ qland, float* __restrict__ kland){
  const int l = blockIdx.x, n = blockIdx.y, e = threadIdx.x;
  const u16* base = Y + (size_t)n*M3*HWN;
  float qs=0.f, ks=0.f;
  #pragma unroll 8
  for(int m=0;m<64;m++){
    size_t off = (size_t)(l*64+m)*M3;
    qs += bf2f(base[off+e]);
    ks += bf2f(base[off+256+e]);
  }
  qland[((size_t)n*LND+l)*EDIM+e] = qs*(1.f/4096.f);
  kland[((size_t)n*LND+l)*EDIM+e] = ks*(1.f/4096.f);
}

// ---------------- Z1[n][j][i] = kland_j · q_i ; Z3[n][i][j] = qland_i · k_j ----------------
__global__ __launch_bounds__(256) void k_landgemm(const u16* __restrict__ Y, const float* __restrict__ qland,
                                                  const float* __restrict__ kland, float* __restrict__ Z1,
                                                  float* __restrict__ Z3){
  const int z = blockIdx.y, n = z>>1, which = z&1;
  const int b0 = blockIdx.x*64;
  const float* land = (which ? qland : kland) + (size_t)n*LND*EDIM;
  const int boff = which ? 256 : 0;
  float* out = (which ? Z3 : Z1) + (size_t)n*LND*HWN;
  const u16* Yb = Y + (size_t)n*M3*HWN;
  __shared__ float Ls[32][68];
  __shared__ float Bs[32][68];
  const int tid = threadIdx.x, tx = tid&15, ty = tid>>4;
  float acc[4][4] = {};
  for(int e0=0;e0<EDIM;e0+=32){
    {
      int a = tid>>2, e8 = (tid&3)*8;
      const float* lp = land + (size_t)a*EDIM + e0 + e8;
      float4 v0 = *(const float4*)lp, v1 = *(const float4*)(lp+4);
      Ls[e8+0][a]=v0.x; Ls[e8+1][a]=v0.y; Ls[e8+2][a]=v0.z; Ls[e8+3][a]=v0.w;
      Ls[e8+4][a]=v1.x; Ls[e8+5][a]=v1.y; Ls[e8+6][a]=v1.z; Ls[e8+7][a]=v1.w;
      const u16* bp = Yb + (size_t)(b0+a)*M3 + boff + e0 + e8;
      ushort4 u0 = *(const ushort4*)bp, u1 = *(const ushort4*)(bp+4);
      Bs[e8+0][a]=bf2f(u0.x); Bs[e8+1][a]=bf2f(u0.y); Bs[e8+2][a]=bf2f(u0.z); Bs[e8+3][a]=bf2f(u0.w);
      Bs[e8+4][a]=bf2f(u1.x); Bs[e8+5][a]=bf2f(u1.y); Bs[e8+6][a]=bf2f(u1.z); Bs[e8+7][a]=bf2f(u1.w);
    }
    __syncthreads();
    #pragma unroll
    for(int e=0;e<32;e++){
      f32x4 a = *(f32x4*)&Ls[e][ty*4];
      f32x4 b = *(f32x4*)&Bs[e][tx*4];
      #pragma unroll
      for(int s=0;s<4;s++)
        #pragma unroll
        for(int u=0;u<4;u++) acc[s][u] += a[s]*b[u];
    }
    __syncthreads();
  }
  #pragma unroll
  for(int s=0;s<4;s++){
    float4 fv = make_float4(acc[s][0],acc[s][1],acc[s][2],acc[s][3]);
    *(float4*)&out[(size_t)(ty*4+s)*HWN + b0 + tx*4] = fv;
  }
}

// ---------------- softmax of Z1 over contiguous 4096 ----------------
__global__ void k_soft1(float* __restrict__ Z1){
  const int b = blockIdx.x, n = b>>6, j = b&63, tid = threadIdx.x;
  float* base = Z1 + ((size_t)n*LND + j)*HWN;
  float v[16];
  float m = -1e30f;
  #pragma unroll
  for(int r=0;r<16;r++){ v[r] = base[r*256 + tid]; m = fmaxf(m, v[r]); }
  #pragma unroll
  for(int o=32;o;o>>=1) m = fmaxf(m, __shfl_xor(m, o));
  __shared__ float redm[4], reds[4];
  const int wid = tid>>6;
  if((tid&63)==0) redm[wid] = m;
  __syncthreads();
  m = fmaxf(fmaxf(redm[0],redm[1]), fmaxf(redm[2],redm[3]));
  float s = 0.f;
  #pragma unroll
  for(int r=0;r<16;r++){ v[r] = __expf(v[r]-m); s += v[r]; }
  #pragma unroll
  for(int o=32;o;o>>=1) s += __shfl_xor(s, o);
  if((tid&63)==0) reds[wid] = s;
  __syncthreads();
  s = reds[0]+reds[1]+reds[2]+reds[3];
  float inv = 1.f/s;
  #pragma unroll
  for(int r=0;r<16;r++) base[r*256 + tid] = v[r]*inv;
}

// ---------------- softmax of Z3 over the 64-landmark (strided) dim ----------------
__global__ void k_soft3(float* __restrict__ Z3){
  const int n = blockIdx.y;
  const int j = blockIdx.x*256 + threadIdx.x;
  float* base = Z3 + (size_t)n*LND*HWN + j;
  float v[64];
  float m = -1e30f;
  #pragma unroll
  for(int i=0;i<64;i++){ v[i] = base[(size_t)i*HWN]; m = fmaxf(m, v[i]); }
  float s = 0.f;
  #pragma unroll
  for(int i=0;i<64;i++){ v[i] = __expf(v[i]-m); s += v[i]; }
  float inv = 1.f/s;
  #pragma unroll
  for(int i=0;i<64;i++) base[(size_t)i*HWN] = v[i]*inv;
}

// ---------------- NS 64x64 matmul via bf16 MFMA: C = L * R, R given transposed (Rt[n][k]) -------
// A-frag: L[m=16wv+c][k=32kt+8q+j]; B-frag: Rt[n=16tc+c][k]; C/D: row=16wv+4q+r, col=16tc+c
__device__ __forceinline__ void ns_mm(const u16* L, const u16* Rt, int wv, int q, int c, f32x4 r4[4]){
  short8 a0 = *(const short8*)(L + (size_t)(16*wv + c)*NS2 + 8*q);
  short8 a1 = *(const short8*)(L + (size_t)(16*wv + c)*NS2 + 32 + 8*q);
  #pragma unroll
  for(int tc=0;tc<4;tc++){
    f32x4 acc = {0.f,0.f,0.f,0.f};
    short8 b0 = *(const short8*)(Rt + (size_t)(16*tc + c)*NS2 + 8*q);
    short8 b1 = *(const short8*)(Rt + (size_t)(16*tc + c)*NS2 + 32 + 8*q);
    acc = __builtin_amdgcn_mfma_f32_16x16x32_bf16(a0, b0, acc, 0, 0, 0);
    acc = __builtin_amdgcn_mfma_f32_16x16x32_bf16(a1, b1, acc, 0, 0, 0);
    r4[tc] = acc;
  }
}

// ---------------- k2 + Newton-Schulz pseudo-inverse, bf16 MFMA ----------------
__global__ __launch_bounds__(256) void k_ns(const float* __restrict__ qland, const float* __restrict__ kland,
                                            float* __restrict__ KinvT){
  __shared__ u16 Kb[64*NS2], Vb[64*NS2], Vt[64*NS2], KVb[64*NS2], KVt[64*NS2], Tt[64*NS2];
  __shared__ float sS[64*68];
  __shared__ float sred[130];
  const int tid = threadIdx.x, n = blockIdx.x;
  const int wv = tid>>6, q = (tid>>4)&3, c = tid&15;
  const float* qb = qland + (size_t)n*LND*EDIM;
  const float* kb = kland + (size_t)n*LND*EDIM;
  // ---- phase 1: S = Qland · Kland^T via MFMA, 4 e-chunks staged in KVb/KVt ----
  f32x4 acc[4];
  #pragma unroll
  for(int t=0;t<4;t++){ acc[t][0]=0.f; acc[t][1]=0.f; acc[t][2]=0.f; acc[t][3]=0.f; }
  for(int e0=0;e0<EDIM;e0+=64){
    __syncthreads();
    {
      int row = tid>>2, c0 = (tid&3)*16;
      const float* qp = qb + (size_t)row*EDIM + e0 + c0;
      const float* kp = kb + (size_t)row*EDIM + e0 + c0;
      u16* qd = &KVb[row*NS2 + c0];
      u16* kd = &KVt[row*NS2 + c0];
      #pragma unroll
      for(int j=0;j<16;j+=4){
        float4 qv = *(const float4*)(qp+j);
        float4 kv = *(const float4*)(kp+j);
        ushort4 qo, ko;
        qo.x=f2bf(qv.x); qo.y=f2bf(qv.y); qo.z=f2bf(qv.z); qo.w=f2bf(qv.w);
        ko.x=f2bf(kv.x); ko.y=f2bf(kv.y); ko.z=f2bf(kv.z); ko.w=f2bf(kv.w);
        *(ushort4*)(qd+j) = qo;
        *(ushort4*)(kd+j) = ko;
      }
    }
    __syncthreads();
    {
      short8 a0 = *(const short8*)&KVb[(16*wv+c)*NS2 + 8*q];
      short8 a1 = *(const short8*)&KVb[(16*wv+c)*NS2 + 32 + 8*q];
      #pragma unroll
      for(int tc=0;tc<4;tc++){
        short8 b0 = *(const short8*)&KVt[(16*tc+c)*NS2 + 8*q];
        short8 b1 = *(const short8*)&KVt[(16*tc+c)*NS2 + 32 + 8*q];
        acc[tc] = __builtin_amdgcn_mfma_f32_16x16x32_bf16(a0, b0, acc[tc], 0, 0, 0);
        acc[tc] = __builtin_amdgcn_mfma_f32_16x16x32_bf16(a1, b1, acc[tc], 0, 0, 0);
      }
    }
  }
  #pragma unroll
  for(int tc=0;tc<4;tc++){
    int col = 16*tc + c, row0 = 16*wv + 4*q;
    sS[(row0+0)*68+col] = acc[tc][0];
    sS[(row0+1)*68+col] = acc[tc][1];
    sS[(row0+2)*68+col] = acc[tc][2];
    sS[(row0+3)*68+col] = acc[tc][3];
  }
  __syncthreads();
  // ---- column softmax (axis=-2) -> Kb (bf16); column abs-sums ----
  if(tid < 64){
    int j = tid;
    float m = -1e30f;
    for(int i=0;i<64;i++) m = fmaxf(m, sS[i*68+j]);
    float ssum = 0.f;
    for(int i=0;i<64;i++) ssum += __expf(sS[i*68+j]-m);
    float inv = 1.f/ssum, cs = 0.f;
    for(int i=0;i<64;i++){
      float kv = __expf(sS[i*68+j]-m)*inv;
      cs += fabsf(kv);
      Kb[i*NS2+j] = f2bf(kv);
    }
    sred[j] = cs;
  }
  __syncthreads();
  if(tid < 64){
    int i = tid; float rs = 0.f;
    for(int j=0;j<64;j++) rs += fabsf(bf2f(Kb[i*NS2+j]));
    sred[64+i] = rs;
  }
  __syncthreads();
  if(tid == 0){
    float v0=-1e30f, vi=-1e30f;
    for(int t=0;t<64;t++){ v0 = fmaxf(v0, sred[t]); vi = fmaxf(vi, sred[64+t]); }
    sred[128] = 1.f/(v0*vi);
  }
  __syncthreads();
  { // V = K^T * sc  (Vb row-major; Vt = V^T)
    float sc = sred[128];
    int i = tid>>2, j16 = (tid&3)*16;
    #pragma unroll
    for(int jj=0;jj<16;jj++){
      int j = j16+jj;
      u16 bvv = f2bf(bf2f(Kb[j*NS2+i])*sc);
      Vb[i*NS2+j] = bvv;
      Vt[j*NS2+i] = bvv;
    }
  }
  __syncthreads();
  // ---- 6 NS iterations via MFMA ----
  f32x4 r4[4];
  for(int it=0; it<6; it++){
    ns_mm(Kb, Vt, wv, q, c, r4);                 // KV = K*V
    #pragma unroll
    for(int tc=0;tc<4;tc++){
      int col = 16*tc + c, row0 = 16*wv + 4*q;
      ushort4 pk;
      pk.x = f2bf(r4[tc][0]); pk.y = f2bf(r4[tc][1]); pk.z = f2bf(r4[tc][2]); pk.w = f2bf(r4[tc][3]);
      KVb[(row0+0)*NS2+col] = pk.x; KVb[(row0+1)*NS2+col] = pk.y;
      KVb[(row0+2)*NS2+col] = pk.z; KVb[(row0+3)*NS2+col] = pk.w;
      *(ushort4*)&KVt[(size_t)col*NS2 + row0] = pk;
    }
    __syncthreads();
    ns_mm(KVb, KVt, wv, q, c, r4);               // KV*KV
    #pragma unroll
    for(int tc=0;tc<4;tc++){                     // T1 = 7KV - KV^2 (transposed store)
      int col = 16*tc+c, row0 = 16*wv+4*q;
      ushort4 pk;
      #pragma unroll
      for(int r=0;r<4;r++){
        float kvv = bf2f(KVb[(row0+r)*NS2+col]);
        ((u16*)&pk)[r] = f2bf(7.f*kvv - r4[tc][r]);
      }
      *(ushort4*)&Tt[(size_t)col*NS2 + row0] = pk;
    }
    __syncthreads();
    ns_mm(KVb, Tt, wv, q, c, r4);                // KV*T1
    __syncthreads();                             // Tt rewritten next while others may still read
    #pragma unroll
    for(int tc=0;tc<4;tc++){                     // T2 = 15KV - KV*T1
      int col = 16*tc+c, row0 = 16*wv+4*q;
      ushort4 pk;
      #pragma unroll
      for(int r=0;r<4;r++){
        float kvv = bf2f(KVb[(row0+r)*NS2+col]);
        ((u16*)&pk)[r] = f2bf(15.f*kvv - r4[tc][r]);
      }
      *(ushort4*)&Tt[(size_t)col*NS2 + row0] = pk;
    }
    __syncthreads();
    ns_mm(Vb, Tt, wv, q, c, r4);                 // V*T2
    __syncthreads();                             // Vb/Vt rewritten next
    #pragma unroll
    for(int tc=0;tc<4;tc++){                     // V = 0.25*(13V - V*T2)
      int col = 16*tc+c, row0 = 16*wv+4*q;
      float nv[4]; ushort4 pk;
      #pragma unroll
      for(int r=0;r<4;r++){
        float vv = bf2f(Vb[(row0+r)*NS2+col]);
        nv[r] = 0.25f*(13.f*vv - r4[tc][r]);
        u16 bb = f2bf(nv[r]);
        Vb[(row0+r)*NS2+col] = bb;
        ((u16*)&pk)[r] = bb;
      }
      *(ushort4*)&Vt[(size_t)col*NS2 + row0] = pk;
      if(it==5){
        *(float4*)&KinvT[(size_t)n*4096 + (size_t)col*64 + row0] = make_float4(nv[0],nv[1],nv[2],nv[3]);
      }
    }
    __syncthreads();
  }
}

// ---------------- partial k3@v: part[n][kc][64][256] ----------------
#define NSTR 72
__global__ __launch_bounds__(256) void k_f(const float* __restrict__ Z3, const u16* __restrict__ Y,
                                           float* __restrict__ part){
  const int kc = blockIdx.x, n = blockIdx.y, tid = threadIdx.x;
  const int jb = kc*128;
  __shared__ u16 k3T[128*NSTR];
  const float* z3b = Z3 + (size_t)n*LND*HWN;
  {
    int ibase = (tid>>5)*8, j4 = (tid&31)*4;
    #pragma unroll
    for(int r=0;r<8;r++){
      int i = ibase + r;
      float4 v = *(const float4*)&z3b[(size_t)i*HWN + jb + j4];
      k3T[(j4+0)*NSTR + i] = f2bf(v.x);
      k3T[(j4+1)*NSTR + i] = f2bf(v.y);
      k3T[(j4+2)*NSTR + i] = f2bf(v.z);
      k3T[(j4+3)*NSTR + i] = f2bf(v.w);
    }
  }
  __syncthreads();
  const int i0 = (tid>>4)*4, e0 = (tid&15)*16;
  const u16* Yb = Y + (size_t)n*M3*HWN;
  float acc[4][16] = {};
  for(int j=0;j<128;j++){
    ushort4 av = *(const ushort4*)&k3T[(size_t)j*NSTR + i0];
    float a0 = bf2f(av.x), a1 = bf2f(av.y), a2 = bf2f(av.z), a3 = bf2f(av.w);
    const u16* vp = Yb + (size_t)(jb+j)*M3 + 512 + e0;
    uint4 U0 = *(const uint4*)vp;
    uint4 U1 = *(const uint4*)(vp+8);
    float bv[16];
    bf2x2(U0.x, bv[0], bv[1]);  bf2x2(U0.y, bv[2], bv[3]);
    bf2x2(U0.z, bv[4], bv[5]);  bf2x2(U0.w, bv[6], bv[7]);
    bf2x2(U1.x, bv[8], bv[9]);  bf2x2(U1.y, bv[10], bv[11]);
    bf2x2(U1.z, bv[12], bv[13]); bf2x2(U1.w, bv[14], bv[15]);
    #pragma unroll
    for(int u=0;u<16;u++){
      acc[0][u] += a0*bv[u];
      acc[1][u] += a1*bv[u];
      acc[2][u] += a2*bv[u];
      acc[3][u] += a3*bv[u];
    }
  }
  float* pb = part + ((size_t)n*32 + kc)*LND*EDIM;
  #pragma unroll
  for(int s=0;s<4;s++)
    #pragma unroll
    for(int t=0;t<16;t+=4){
      float4 fv = make_float4(acc[s][t],acc[s][t+1],acc[s][t+2],acc[s][t+3]);
      *(float4*)&pb[(size_t)(i0+s)*EDIM + e0 + t] = fv;
    }
}

__global__ void k_fred(const float* __restrict__ part, float* __restrict__ B3){
  const int idx = blockIdx.x*256 + threadIdx.x;
  const int n = idx >> 14, rem = idx & 16383;
  const float* p = part + (size_t)n*32*16384 + rem;
  float s = 0.f;
  #pragma unroll
  for(int kc=0;kc<32;kc++) s += p[(size_t)kc*16384];
  B3[idx] = s;
}

// ---------------- C2[j][e] = sum_l Kinv[j][l]*B3[l][e] ----------------
__global__ __launch_bounds__(256) void k_c2(const float* __restrict__ KinvT, const float* __restrict__ B3,
                                            float* __restrict__ C2){
  const int eb = blockIdx.x*64, n = blockIdx.y, tid = threadIdx.x;
  __shared__ float KT[64][68];
  __shared__ float Bs2[64][68];
  {
    int l = tid>>2, o16 = (tid&3)*16;
    const float* kp = KinvT + (size_t)n*4096 + l*64 + o16;
    const float* bp = B3 + ((size_t)n*LND + l)*EDIM + eb + o16;
    #pragma unroll
    for(int t=0;t<16;t+=4){
      *(float4*)&KT[l][o16+t]  = *(const float4*)(kp+t);
      *(float4*)&Bs2[l][o16+t] = *(const float4*)(bp+t);
    }
  }
  __syncthreads();
  const int j0 = (tid>>4)*4, u0 = (tid&15)*4;
  float acc[4][4] = {};
  #pragma unroll 8
  for(int l=0;l<64;l++){
    f32x4 a = *(f32x4*)&KT[l][j0];
    f32x4 b = *(f32x4*)&Bs2[l][u0];
    #pragma unroll
    for(int s=0;s<4;s++)
      #pragma unroll
      for(int u=0;u<4;u++) acc[s][u] += a[s]*b[u];
  }
  #pragma unroll
  for(int s=0;s<4;s++){
    float4 fv = make_float4(acc[s][0],acc[s][1],acc[s][2],acc[s][3]);
    *(float4*)&C2[((size_t)n*LND + j0+s)*EDIM + eb + u0] = fv;
  }
}

// ---------------- out[i][e] = sum_j k1t[j][i]*C2[j][e] + v[i][e]; OM bf16 ----------------
__global__ __launch_bounds__(256) void k_out(const float* __restrict__ Z1, const float* __restrict__ C2,
                                             const u16* __restrict__ Y, u16* __restrict__ OM){
  const int ib = blockIdx.x*64, n = blockIdx.y, tid = threadIdx.x;
  __shared__ float K1s[64][68];
  __shared__ u16 C2s[64*264];
  {
    int j = tid>>2, i16 = (tid&3)*16;
    const float* zp = Z1 + ((size_t)n*LND + j)*HWN + ib + i16;
    #pragma unroll
    for(int t=0;t<16;t+=4) *(float4*)&K1s[j][i16+t] = *(const float4*)(zp+t);
    int e64 = (tid&3)*64;
    const float* cp = C2 + ((size_t)n*LND + j)*EDIM + e64;
    #pragma unroll
    for(int t=0;t<64;t+=4){
      float4 v = *(const float4*)(cp+t);
      C2s[j*264 + e64+t+0] = f2bf(v.x);
      C2s[j*264 + e64+t+1] = f2bf(v.y);
      C2s[j*264 + e64+t+2] = f2bf(v.z);
      C2s[j*264 + e64+t+3] = f2bf(v.w);
    }
  }
  __syncthreads();
  const int i0 = (tid>>4)*4, e0 = (tid&15)*16;
  float acc[4][16] = {};
  for(int j=0;j<64;j++){
    f32x4 a = *(f32x4*)&K1s[j][i0];
    const u16* cb = &C2s[j*264 + e0];
    uint4 U0 = *(const uint4*)cb;
    uint4 U1 = *(const uint4*)(cb+8);
    float bv[16];
    bf2x2(U0.x, bv[0], bv[1]);  bf2x2(U0.y, bv[2], bv[3]);
    bf2x2(U0.z, bv[4], bv[5]);  bf2x2(U0.w, bv[6], bv[7]);
    bf2x2(U1.x, bv[8], bv[9]);  bf2x2(U1.y, bv[10], bv[11]);
    bf2x2(U1.z, bv[12], bv[13]); bf2x2(U1.w, bv[14], bv[15]);
    #pragma unroll
    for(int u=0;u<16;u++){
      acc[0][u] += a[0]*bv[u];
      acc[1][u] += a[1]*bv[u];
      acc[2][u] += a[2]*bv[u];
      acc[3][u] += a[3]*bv[u];
    }
  }
  const u16* Yb = Y + (size_t)n*M3*HWN;
  u16* ob = OM + (size_t)n*HWN*EDIM;
  #pragma unroll
  for(int s=0;s<4;s++){
    int i = ib + i0 + s;
    const u16* vp = Yb + (size_t)i*M3 + 512 + e0;
    uint4 U0 = *(const uint4*)vp, U1 = *(const uint4*)(vp+8);
    float vv[16];
    bf2x2(U0.x, vv[0], vv[1]);  bf2x2(U0.y, vv[2], vv[3]);
    bf2x2(U0.z, vv[4], vv[5]);  bf2x2(U0.w, vv[6], vv[7]);
    bf2x2(U1.x, vv[8], vv[9]);  bf2x2(U1.y, vv[10], vv[11]);
    bf2x2(U1.z, vv[12], vv[13]); bf2x2(U1.w, vv[14], vv[15]);
    #pragma unroll
    for(int t=0;t<16;t+=4){
      ushort4 o;
      o.x = f2bf(acc[s][t+0]+vv[t+0]);
      o.y = f2bf(acc[s][t+1]+vv[t+1]);
      o.z = f2bf(acc[s][t+2]+vv[t+2]);
      o.w = f2bf(acc[s][t+3]+vv[t+3]);
      *(ushort4*)&ob[(size_t)i*EDIM + e0 + t] = o;
    }
  }
}

// ---------------- transpose of raw-reshaped OM ----------------
__global__ __launch_bounds__(256) void k_trans2(const u16* __restrict__ OM, u16* __restrict__ OMT){
  __shared__ u16 Ts[64*65];
  const int bi = blockIdx.x;
  const int n = bi>>8, rem = bi&255, et = rem>>6, pt = rem&63;
  const int e0 = et*64, p0 = pt*64, tid = threadIdx.x;
  const u16* omb = OM + (size_t)n*HWN*EDIM;
  {
    int ee = tid>>2, pj = (tid&3)*16;
    const u16* ip = omb + (size_t)(e0+ee)*HWN + p0 + pj;
    ushort4 v0 = *(const ushort4*)(ip);
    ushort4 v1 = *(const ushort4*)(ip+4);
    ushort4 v2 = *(const ushort4*)(ip+8);
    ushort4 v3 = *(const ushort4*)(ip+12);
    u16* tp = &Ts[ee*65 + pj];
    tp[0]=v0.x; tp[1]=v0.y; tp[2]=v0.z; tp[3]=v0.w;
    tp[4]=v1.x; tp[5]=v1.y; tp[6]=v1.z; tp[7]=v1.w;
    tp[8]=v2.x; tp[9]=v2.y; tp[10]=v2.z; tp[11]=v2.w;
    tp[12]=v3.x; tp[13]=v3.y; tp[14]=v3.z; tp[15]=v3.w;
  }
  __syncthreads();
  {
    int pp = tid>>2, ej = (tid&3)*16;
    u16* op = OMT + ((size_t)n*HWN + p0 + pp)*EDIM + e0 + ej;
    ushort4 o[4];
    #pragma unroll
    for(int j=0;j<16;j++) ((u16*)o)[j] = Ts[(ej+j)*65 + pp];
    *(ushort4*)(op+0)  = o[0];
    *(ushort4*)(op+4)  = o[1];
    *(ushort4*)(op+8)  = o[2];
    *(ushort4*)(op+12) = o[3];
  }
}

// ---------------- proj GEMM 128x128xK256 ----------------
__global__ __launch_bounds__(256) void k_proj(const float* __restrict__ w, const u16* __restrict__ OMT,
                                              const float* __restrict__ bias, float* __restrict__ out){
  __shared__ u16 As[128*KS2];
  __shared__ u16 Bs[128*KS2];
  const int bi = blockIdx.x;
  const int n = bi&7, rem = bi>>3;
  const int ch0 = (rem&1)*128, p0 = (rem>>1)*128;
  const int tid = threadIdx.x;
  const int c = tid&15, qq = (tid>>4)&3, w4 = tid>>6;
  const int wr0 = (w4&1)*64, wc0 = (w4>>1)*64;
  const u16* xb = OMT + ((size_t)n*HWN + p0)*EDIM;
  f32x4 acc[4][4];
  #pragma unroll
  for(int mt=0;mt<4;mt++)
    #pragma unroll
    for(int nt=0;nt<4;nt++){ acc[mt][nt][0]=0.f; acc[mt][nt][1]=0.f; acc[mt][nt][2]=0.f; acc[mt][nt][3]=0.f; }
  const int ra = tid&127, ca = tid>>7;
  for(int ph=0; ph<2; ph++){
    {
      const float* ga = w + (size_t)(ch0+ra)*EDIM + ph*128 + ca*64;
      u16* la = &As[ra*KS2 + ca*64];
      #pragma unroll
      for(int j=0;j<8;j++){
        float4 v0 = *(const float4*)(ga + j*8);
        float4 v1 = *(const float4*)(ga + j*8 + 4);
        ushort4 o0, o1;
        o0.x=f2bf(v0.x); o0.y=f2bf(v0.y); o0.z=f2bf(v0.z); o0.w=f2bf(v0.w);
        o1.x=f2bf(v1.x); o1.y=f2bf(v1.y); o1.z=f2bf(v1.z); o1.w=f2bf(v1.w);
        *(ushort4*)(la + j*8)     = o0;
        *(ushort4*)(la + j*8 + 4) = o1;
      }
    }
    {
      const u16* gb = xb + (size_t)ra*EDIM + ph*128 + ca*64;
      u16* lb = &Bs[ra*KS2 + ca*64];
      #pragma unroll
      for(int j=0;j<8;j++)
        *(short8*)(lb + j*8) = *(const short8*)(gb + j*8);
    }
    __syncthreads();
    #pragma unroll
    for(int kt=0;kt<4;kt++){
      short8 af[4], bf[4];
      #pragma unroll
      for(int mt=0;mt<4;mt++) af[mt] = *(const short8*)&As[(wr0+mt*16+c)*KS2 + kt*32 + qq*8];
      #pragma unroll
      for(int nt=0;nt<4;nt++) bf[nt] = *(const short8*)&Bs[(wc0+nt*16+c)*KS2 + kt*32 + qq*8];
      #pragma unroll
      for(int mt=0;mt<4;mt++)
        #pragma unroll
        for(int nt=0;nt<4;nt++)
          acc[mt][nt] = __builtin_amdgcn_mfma_f32_16x16x32_bf16(af[mt], bf[nt], acc[mt][nt], 0, 0, 0);
    }
    __syncthreads();
  }
  float* ob = out + (size_t)n*EDIM*HWN;
  #pragma unroll
  for(int mt=0;mt<4;mt++){
    int chb = ch0 + wr0 + mt*16 + 4*qq;
    float b0 = bias[chb], b1 = bias[chb+1], b2 = bias[chb+2], b3 = bias[chb+3];
    #pragma unroll
    for(int nt=0;nt<4;nt++){
      int p = p0 + wc0 + nt*16 + c;
      float* yp = ob + (size_t)chb*HWN + p;
      yp[0]             = acc[mt][nt][0]+b0;
      yp[HWN]           = acc[mt][nt][1]+b1;
      yp[2*(size_t)HWN] = acc[mt][nt][2]+b2;
      yp[3*(size_t)HWN] = acc[mt][nt][3]+b3;
    }
  }
}

extern "C" void kernel_launch(void* const* d_in, const int* in_sizes, int n_in,
                              void* d_out, int out_size, void* d_ws, size_t ws_size,
                              hipStream_t stream){
  (void)out_size; (void)ws_size;
  const float* x     = (const float*)d_in[0];
  const float* w_qkv = (const float*)d_in[1];
  const float* b_qkv = (const float*)d_in[2];
  const float* w_out = (const float*)d_in[3];
  const float* b_out = (const float*)d_in[4];
  for(int i=0;i<n_in;i++){
    switch(in_sizes[i]){
      case 8388608: x     = (const float*)d_in[i]; break;
      case 196608:  w_qkv = (const float*)d_in[i]; break;
      case 768:     b_qkv = (const float*)d_in[i]; break;
      case 65536:   w_out = (const float*)d_in[i]; break;
      case 256:     b_out = (const float*)d_in[i]; break;
      default: break;
    }
  }
  float* out = (float*)d_out;
  char* ws = (char*)d_ws;

  u16*   Y     = (u16*)(ws + 0);              // 50,331,648 B  bf16 [8][768*4096]
  float* qland = (float*)(ws + 50331648);
  float* kland = (float*)(ws + 50855936);
  float* Z1    = (float*)(ws + 51380224);
  float* Z3    = (float*)(ws + 59768832);
  float* KinvT = (float*)(ws + 68157440);
  u16*   Xt    = (u16*)(ws + 68288512);       // 16 MB region: Xt -> part -> OMT
  float* part  = (float*)(ws + 68288512);
  u16*   OMT   = (u16*)(ws + 68288512);
  float* B3    = (float*)(ws + 85065728);
  float* C2    = (float*)(ws + 85590016);
  u16*   OM    = (u16*)(ws + 86114304);       // 16 MB bf16

  k_prep    <<<dim3(2048),  256, 0, stream>>>(x, Xt);
  k_qkv     <<<dim3(1536),  256, 0, stream>>>(w_qkv, Xt, b_qkv, Y);
  k_land    <<<dim3(64,8),  256, 0, stream>>>(Y, qland, kland);
  k_landgemm<<<dim3(64,16), 256, 0, stream>>>(Y, qland, kland, Z1, Z3);
  k_soft1   <<<dim3(512),   256, 0, stream>>>(Z1);
  k_soft3   <<<dim3(16,8),  256, 0, stream>>>(Z3);
  k_ns      <<<dim3(8),     256, 0, stream>>>(qland, kland, KinvT);
  k_f       <<<dim3(32,8),  256, 0, stream>>>(Z3, Y, part);
  k_fred    <<<dim3(512),   256, 0, stream>>>(part, B3);
  k_c2      <<<dim3(4,8),   256, 0, stream>>>(KinvT, B3, C2);
  k_out     <<<dim3(64,8),  256, 0, stream>>>(Z1, C2, Y, OM);
  k_trans2  <<<dim3(2048),  256, 0, stream>>>(OM, OMT);
  k_proj    <<<dim3(512),   256, 0, stream>>>(w_out, OMT, b_out, out);
}

// Round 8
// 286.179 us; speedup vs baseline: 1.7313x; 1.1619x over previous
//
#include <hip/hip_runtime.h>
#include <hip/hip_bf16.h>

typedef unsigned short u16;
typedef __attribute__((ext_vector_type(4))) float f32x4;
typedef __attribute__((ext_vector_type(8))) short short8;

#define NB   8
#define CIN  256
#define EDIM 256
#define M3   768
#define HWN  4096
#define LND  64
#define KS2  136   // GEMM LDS row stride (bf16 elems): 272B, 16B aligned
#define NS2  72    // NS LDS row stride (bf16 elems): 144B, 16B aligned

__device__ __forceinline__ float bf2f(u16 u){ return __uint_as_float(((unsigned)u)<<16); }
__device__ __forceinline__ u16 f2bf(float f){ __hip_bfloat16 h = __float2bfloat16(f); return *reinterpret_cast<u16*>(&h); }
__device__ __forceinline__ void bf2x2(unsigned u, float &lo, float &hi){
  lo = __uint_as_float(u<<16);
  hi = __uint_as_float(u & 0xffff0000u);
}

// ---------------- prep: Xt[n][p][c] (bf16) = transpose of X[n][c][p] (fp32) ----------------
__global__ __launch_bounds__(256) void k_prep(const float* __restrict__ x, u16* __restrict__ Xt){
  __shared__ float Ts[64*65];
  const int bi = blockIdx.x;
  const int n = bi>>8, rem = bi&255, ct = rem>>6, pt = rem&63;
  const int c0 = ct*64, p0 = pt*64, tid = threadIdx.x;
  {
    int cc = tid>>2, pj = (tid&3)*16;
    const float* xp = x + (size_t)n*CIN*HWN + (size_t)(c0+cc)*HWN + p0 + pj;
    #pragma unroll
    for(int j=0;j<16;j++) Ts[cc*65 + pj + j] = xp[j];
  }
  __syncthreads();
  {
    int pp = tid>>2, ej = (tid&3)*16;
    u16* op = Xt + ((size_t)n*HWN + p0 + pp)*CIN + c0 + ej;
    ushort4 o[4];
    #pragma unroll
    for(int j=0;j<16;j++) ((u16*)o)[j] = f2bf(Ts[(ej+j)*65 + pp]);
    *(ushort4*)(op+0)  = o[0];
    *(ushort4*)(op+4)  = o[1];
    *(ushort4*)(op+8)  = o[2];
    *(ushort4*)(op+12) = o[3];
  }
}

// ---------------- QKV GEMM 128x128xK256 bf16 MFMA ----------------
__global__ __launch_bounds__(256) void k_qkv(const float* __restrict__ w, const u16* __restrict__ Xt,
                                             const float* __restrict__ bias, u16* __restrict__ Y){
  __shared__ u16 As[128*KS2];
  __shared__ u16 Bs[128*KS2];
  const int bi = blockIdx.x;
  const int n = bi&7, rem = bi>>3;
  const int ch0 = (rem%6)*128, p0 = (rem/6)*128;
  const int tid = threadIdx.x;
  const int c = tid&15, qq = (tid>>4)&3, w4 = tid>>6;
  const int wr0 = (w4&1)*64, wc0 = (w4>>1)*64;
  const u16* xb = Xt + ((size_t)n*HWN + p0)*CIN;
  f32x4 acc[4][4];
  #pragma unroll
  for(int mt=0;mt<4;mt++)
    #pragma unroll
    for(int nt=0;nt<4;nt++){ acc[mt][nt][0]=0.f; acc[mt][nt][1]=0.f; acc[mt][nt][2]=0.f; acc[mt][nt][3]=0.f; }
  const int ra = tid&127, ca = tid>>7;
  for(int ph=0; ph<2; ph++){
    {
      const float* ga = w + (size_t)(ch0+ra)*CIN + ph*128 + ca*64;
      u16* la = &As[ra*KS2 + ca*64];
      #pragma unroll
      for(int j=0;j<8;j++){
        float4 v0 = *(const float4*)(ga + j*8);
        float4 v1 = *(const float4*)(ga + j*8 + 4);
        ushort4 o0, o1;
        o0.x=f2bf(v0.x); o0.y=f2bf(v0.y); o0.z=f2bf(v0.z); o0.w=f2bf(v0.w);
        o1.x=f2bf(v1.x); o1.y=f2bf(v1.y); o1.z=f2bf(v1.z); o1.w=f2bf(v1.w);
        *(ushort4*)(la + j*8)     = o0;
        *(ushort4*)(la + j*8 + 4) = o1;
      }
    }
    {
      const u16* gb = xb + (size_t)ra*CIN + ph*128 + ca*64;
      u16* lb = &Bs[ra*KS2 + ca*64];
      #pragma unroll
      for(int j=0;j<8;j++)
        *(short8*)(lb + j*8) = *(const short8*)(gb + j*8);
    }
    __syncthreads();
    #pragma unroll
    for(int kt=0;kt<4;kt++){
      short8 af[4], bf[4];
      #pragma unroll
      for(int mt=0;mt<4;mt++) af[mt] = *(const short8*)&As[(wr0+mt*16+c)*KS2 + kt*32 + qq*8];
      #pragma unroll
      for(int nt=0;nt<4;nt++) bf[nt] = *(const short8*)&Bs[(wc0+nt*16+c)*KS2 + kt*32 + qq*8];
      #pragma unroll
      for(int mt=0;mt<4;mt++)
        #pragma unroll
        for(int nt=0;nt<4;nt++)
          acc[mt][nt] = __builtin_amdgcn_mfma_f32_16x16x32_bf16(af[mt], bf[nt], acc[mt][nt], 0, 0, 0);
    }
    __syncthreads();
  }
  u16* Yb = Y + (size_t)n*M3*HWN;
  #pragma unroll
  for(int mt=0;mt<4;mt++){
    int chb = ch0 + wr0 + mt*16 + 4*qq;
    float b0 = bias[chb], b1 = bias[chb+1], b2 = bias[chb+2], b3 = bias[chb+3];
    #pragma unroll
    for(int nt=0;nt<4;nt++){
      int p = p0 + wc0 + nt*16 + c;
      u16* yp = Yb + (size_t)chb*HWN + p;
      yp[0]             = f2bf(acc[mt][nt][0]+b0);
      yp[HWN]           = f2bf(acc[mt][nt][1]+b1);
      yp[2*(size_t)HWN] = f2bf(acc[mt][nt][2]+b2);
      yp[3*(size_t)HWN] = f2bf(acc[mt][nt][3]+b3);
    }
  }
}

// ---------------- landmarks ----------------
__global__ void k_land(const u16* __restrict__ Y, float* __restrict__ qland, float* __restrict__ kland){
  const int l = blockIdx.x, n = blockIdx.y, e = threadIdx.x;
  const u16* base = Y + (size_t)n*M3*HWN;
  float qs=0.f, ks=0.f;
  #pragma unroll 8
  for(int m=0;m<64;m++){
    size_t off = (size_t)(l*64+m)*M3;
    qs += bf2f(base[off+e]);
    ks += bf2f(base[off+256+e]);
  }
  qland[((size_t)n*LND+l)*EDIM+e] = qs*(1.f/4096.f);
  kland[((size_t)n*LND+l)*EDIM+e] = ks*(1.f/4096.f);
}

// ---------------- Z1[n][j][i] = kland_j · q_i ; Z3[n][i][j] = qland_i · k_j (raw logits) --------
__global__ __launch_bounds__(256) void k_landgemm(const u16* __restrict__ Y, const float* __restrict__ qland,
                                                  const float* __restrict__ kland, float* __restrict__ Z1,
                                                  float* __restrict__ Z3){
  const int z = blockIdx.y, n = z>>1, which = z&1;
  const int b0 = blockIdx.x*64;
  const float* land = (which ? qland : kland) + (size_t)n*LND*EDIM;
  const int boff = which ? 256 : 0;
  float* out = (which ? Z3 : Z1) + (size_t)n*LND*HWN;
  const u16* Yb = Y + (size_t)n*M3*HWN;
  __shared__ float Ls[32][68];
  __shared__ float Bs[32][68];
  const int tid = threadIdx.x, tx = tid&15, ty = tid>>4;
  float acc[4][4] = {};
  for(int e0=0;e0<EDIM;e0+=32){
    {
      int a = tid>>2, e8 = (tid&3)*8;
      const float* lp = land + (size_t)a*EDIM + e0 + e8;
      float4 v0 = *(const float4*)lp, v1 = *(const float4*)(lp+4);
      Ls[e8+0][a]=v0.x; Ls[e8+1][a]=v0.y; Ls[e8+2][a]=v0.z; Ls[e8+3][a]=v0.w;
      Ls[e8+4][a]=v1.x; Ls[e8+5][a]=v1.y; Ls[e8+6][a]=v1.z; Ls[e8+7][a]=v1.w;
      const u16* bp = Yb + (size_t)(b0+a)*M3 + boff + e0 + e8;
      ushort4 u0 = *(const ushort4*)bp, u1 = *(const ushort4*)(bp+4);
      Bs[e8+0][a]=bf2f(u0.x); Bs[e8+1][a]=bf2f(u0.y); Bs[e8+2][a]=bf2f(u0.z); Bs[e8+3][a]=bf2f(u0.w);
      Bs[e8+4][a]=bf2f(u1.x); Bs[e8+5][a]=bf2f(u1.y); Bs[e8+6][a]=bf2f(u1.z); Bs[e8+7][a]=bf2f(u1.w);
    }
    __syncthreads();
    #pragma unroll
    for(int e=0;e<32;e++){
      f32x4 a = *(f32x4*)&Ls[e][ty*4];
      f32x4 b = *(f32x4*)&Bs[e][tx*4];
      #pragma unroll
      for(int s=0;s<4;s++)
        #pragma unroll
        for(int u=0;u<4;u++) acc[s][u] += a[s]*b[u];
    }
    __syncthreads();
  }
  #pragma unroll
  for(int s=0;s<4;s++){
    float4 fv = make_float4(acc[s][0],acc[s][1],acc[s][2],acc[s][3]);
    *(float4*)&out[(size_t)(ty*4+s)*HWN + b0 + tx*4] = fv;
  }
}

// ---------------- softmax of Z1 over contiguous 4096 ----------------
__global__ void k_soft1(float* __restrict__ Z1){
  const int b = blockIdx.x, n = b>>6, j = b&63, tid = threadIdx.x;
  float* base = Z1 + ((size_t)n*LND + j)*HWN;
  float v[16];
  float m = -1e30f;
  #pragma unroll
  for(int r=0;r<16;r++){ v[r] = base[r*256 + tid]; m = fmaxf(m, v[r]); }
  #pragma unroll
  for(int o=32;o;o>>=1) m = fmaxf(m, __shfl_xor(m, o));
  __shared__ float redm[4], reds[4];
  const int wid = tid>>6;
  if((tid&63)==0) redm[wid] = m;
  __syncthreads();
  m = fmaxf(fmaxf(redm[0],redm[1]), fmaxf(redm[2],redm[3]));
  float s = 0.f;
  #pragma unroll
  for(int r=0;r<16;r++){ v[r] = __expf(v[r]-m); s += v[r]; }
  #pragma unroll
  for(int o=32;o;o>>=1) s += __shfl_xor(s, o);
  if((tid&63)==0) reds[wid] = s;
  __syncthreads();
  s = reds[0]+reds[1]+reds[2]+reds[3];
  float inv = 1.f/s;
  #pragma unroll
  for(int r=0;r<16;r++) base[r*256 + tid] = v[r]*inv;
}

// ---------------- NS 64x64 matmul via bf16 MFMA ----------------
__device__ __forceinline__ void ns_mm(const u16* L, const u16* Rt, int wv, int q, int c, f32x4 r4[4]){
  short8 a0 = *(const short8*)(L + (size_t)(16*wv + c)*NS2 + 8*q);
  short8 a1 = *(const short8*)(L + (size_t)(16*wv + c)*NS2 + 32 + 8*q);
  #pragma unroll
  for(int tc=0;tc<4;tc++){
    f32x4 acc = {0.f,0.f,0.f,0.f};
    short8 b0 = *(const short8*)(Rt + (size_t)(16*tc + c)*NS2 + 8*q);
    short8 b1 = *(const short8*)(Rt + (size_t)(16*tc + c)*NS2 + 32 + 8*q);
    acc = __builtin_amdgcn_mfma_f32_16x16x32_bf16(a0, b0, acc, 0, 0, 0);
    acc = __builtin_amdgcn_mfma_f32_16x16x32_bf16(a1, b1, acc, 0, 0, 0);
    r4[tc] = acc;
  }
}

// ---------------- k2 + Newton-Schulz pseudo-inverse, bf16 MFMA ----------------
__global__ __launch_bounds__(256) void k_ns(const float* __restrict__ qland, const float* __restrict__ kland,
                                            float* __restrict__ KinvT){
  __shared__ u16 Kb[64*NS2], Vb[64*NS2], Vt[64*NS2], KVb[64*NS2], KVt[64*NS2], Tt[64*NS2];
  __shared__ float sS[64*68];
  __shared__ float sred[130];
  const int tid = threadIdx.x, n = blockIdx.x;
  const int wv = tid>>6, q = (tid>>4)&3, c = tid&15;
  const float* qb = qland + (size_t)n*LND*EDIM;
  const float* kb = kland + (size_t)n*LND*EDIM;
  f32x4 acc[4];
  #pragma unroll
  for(int t=0;t<4;t++){ acc[t][0]=0.f; acc[t][1]=0.f; acc[t][2]=0.f; acc[t][3]=0.f; }
  for(int e0=0;e0<EDIM;e0+=64){
    __syncthreads();
    {
      int row = tid>>2, c0 = (tid&3)*16;
      const float* qp = qb + (size_t)row*EDIM + e0 + c0;
      const float* kp = kb + (size_t)row*EDIM + e0 + c0;
      u16* qd = &KVb[row*NS2 + c0];
      u16* kd = &KVt[row*NS2 + c0];
      #pragma unroll
      for(int j=0;j<16;j+=4){
        float4 qv = *(const float4*)(qp+j);
        float4 kv = *(const float4*)(kp+j);
        ushort4 qo, ko;
        qo.x=f2bf(qv.x); qo.y=f2bf(qv.y); qo.z=f2bf(qv.z); qo.w=f2bf(qv.w);
        ko.x=f2bf(kv.x); ko.y=f2bf(kv.y); ko.z=f2bf(kv.z); ko.w=f2bf(kv.w);
        *(ushort4*)(qd+j) = qo;
        *(ushort4*)(kd+j) = ko;
      }
    }
    __syncthreads();
    {
      short8 a0 = *(const short8*)&KVb[(16*wv+c)*NS2 + 8*q];
      short8 a1 = *(const short8*)&KVb[(16*wv+c)*NS2 + 32 + 8*q];
      #pragma unroll
      for(int tc=0;tc<4;tc++){
        short8 b0 = *(const short8*)&KVt[(16*tc+c)*NS2 + 8*q];
        short8 b1 = *(const short8*)&KVt[(16*tc+c)*NS2 + 32 + 8*q];
        acc[tc] = __builtin_amdgcn_mfma_f32_16x16x32_bf16(a0, b0, acc[tc], 0, 0, 0);
        acc[tc] = __builtin_amdgcn_mfma_f32_16x16x32_bf16(a1, b1, acc[tc], 0, 0, 0);
      }
    }
  }
  #pragma unroll
  for(int tc=0;tc<4;tc++){
    int col = 16*tc + c, row0 = 16*wv + 4*q;
    sS[(row0+0)*68+col] = acc[tc][0];
    sS[(row0+1)*68+col] = acc[tc][1];
    sS[(row0+2)*68+col] = acc[tc][2];
    sS[(row0+3)*68+col] = acc[tc][3];
  }
  __syncthreads();
  if(tid < 64){
    int j = tid;
    float m = -1e30f;
    for(int i=0;i<64;i++) m = fmaxf(m, sS[i*68+j]);
    float ssum = 0.f;
    for(int i=0;i<64;i++) ssum += __expf(sS[i*68+j]-m);
    float inv = 1.f/ssum, cs = 0.f;
    for(int i=0;i<64;i++){
      float kv = __expf(sS[i*68+j]-m)*inv;
      cs += fabsf(kv);
      Kb[i*NS2+j] = f2bf(kv);
    }
    sred[j] = cs;
  }
  __syncthreads();
  if(tid < 64){
    int i = tid; float rs = 0.f;
    for(int j=0;j<64;j++) rs += fabsf(bf2f(Kb[i*NS2+j]));
    sred[64+i] = rs;
  }
  __syncthreads();
  if(tid == 0){
    float v0=-1e30f, vi=-1e30f;
    for(int t=0;t<64;t++){ v0 = fmaxf(v0, sred[t]); vi = fmaxf(vi, sred[64+t]); }
    sred[128] = 1.f/(v0*vi);
  }
  __syncthreads();
  {
    float sc = sred[128];
    int i = tid>>2, j16 = (tid&3)*16;
    #pragma unroll
    for(int jj=0;jj<16;jj++){
      int j = j16+jj;
      u16 bvv = f2bf(bf2f(Kb[j*NS2+i])*sc);
      Vb[i*NS2+j] = bvv;
      Vt[j*NS2+i] = bvv;
    }
  }
  __syncthreads();
  f32x4 r4[4];
  for(int it=0; it<6; it++){
    ns_mm(Kb, Vt, wv, q, c, r4);
    #pragma unroll
    for(int tc=0;tc<4;tc++){
      int col = 16*tc + c, row0 = 16*wv + 4*q;
      ushort4 pk;
      pk.x = f2bf(r4[tc][0]); pk.y = f2bf(r4[tc][1]); pk.z = f2bf(r4[tc][2]); pk.w = f2bf(r4[tc][3]);
      KVb[(row0+0)*NS2+col] = pk.x; KVb[(row0+1)*NS2+col] = pk.y;
      KVb[(row0+2)*NS2+col] = pk.z; KVb[(row0+3)*NS2+col] = pk.w;
      *(ushort4*)&KVt[(size_t)col*NS2 + row0] = pk;
    }
    __syncthreads();
    ns_mm(KVb, KVt, wv, q, c, r4);
    #pragma unroll
    for(int tc=0;tc<4;tc++){
      int col = 16*tc+c, row0 = 16*wv+4*q;
      ushort4 pk;
      #pragma unroll
      for(int r=0;r<4;r++){
        float kvv = bf2f(KVb[(row0+r)*NS2+col]);
        ((u16*)&pk)[r] = f2bf(7.f*kvv - r4[tc][r]);
      }
      *(ushort4*)&Tt[(size_t)col*NS2 + row0] = pk;
    }
    __syncthreads();
    ns_mm(KVb, Tt, wv, q, c, r4);
    __syncthreads();
    #pragma unroll
    for(int tc=0;tc<4;tc++){
      int col = 16*tc+c, row0 = 16*wv+4*q;
      ushort4 pk;
      #pragma unroll
      for(int r=0;r<4;r++){
        float kvv = bf2f(KVb[(row0+r)*NS2+col]);
        ((u16*)&pk)[r] = f2bf(15.f*kvv - r4[tc][r]);
      }
      *(ushort4*)&Tt[(size_t)col*NS2 + row0] = pk;
    }
    __syncthreads();
    ns_mm(Vb, Tt, wv, q, c, r4);
    __syncthreads();
    #pragma unroll
    for(int tc=0;tc<4;tc++){
      int col = 16*tc+c, row0 = 16*wv+4*q;
      float nv[4]; ushort4 pk;
      #pragma unroll
      for(int r=0;r<4;r++){
        float vv = bf2f(Vb[(row0+r)*NS2+col]);
        nv[r] = 0.25f*(13.f*vv - r4[tc][r]);
        u16 bb = f2bf(nv[r]);
        Vb[(row0+r)*NS2+col] = bb;
        ((u16*)&pk)[r] = bb;
      }
      *(ushort4*)&Vt[(size_t)col*NS2 + row0] = pk;
      if(it==5){
        *(float4*)&KinvT[(size_t)n*4096 + (size_t)col*64 + row0] = make_float4(nv[0],nv[1],nv[2],nv[3]);
      }
    }
    __syncthreads();
  }
}

// ---------------- fused soft3 + partial k3@v: part[n][kc][64][eb..eb+128] ----------------
// Block (kc, n, eh): stages raw Z3 logits [64 i][128 j], column-softmax over i (axis=-2),
// then P[64][128] @ V[128][e-half 128] on VALU.
#define NSTR 76
__global__ __launch_bounds__(256) void k_f(const float* __restrict__ Z3, const u16* __restrict__ Y,
                                           float* __restrict__ part){
  const int kc = blockIdx.x, n = blockIdx.y, eh = blockIdx.z, tid = threadIdx.x;
  const int jb = kc*128, eb = eh*128;
  __shared__ float Sf[64*132];      // [i][j] raw logits
  __shared__ u16 k3T[128*NSTR];     // [j][i] post-softmax bf16
  const float* z3b = Z3 + (size_t)n*LND*HWN;
  { // stage logits (coalesced float4)
    int ibase = (tid>>5)*8, j4 = (tid&31)*4;
    #pragma unroll
    for(int r=0;r<8;r++){
      int i = ibase + r;
      *(float4*)&Sf[i*132 + j4] = *(const float4*)&z3b[(size_t)i*HWN + jb + j4];
    }
  }
  __syncthreads();
  if(tid < 128){ // softmax over i for column j=tid (column reads conflict-free)
    int j = tid;
    float m = -1e30f;
    for(int i=0;i<64;i++) m = fmaxf(m, Sf[i*132 + j]);
    float s = 0.f;
    for(int i=0;i<64;i++){ float e = __expf(Sf[i*132 + j] - m); Sf[i*132 + j] = e; s += e; }
    float inv = 1.f/s;
    u16* kr = &k3T[j*NSTR];
    for(int i=0;i<64;i+=4){
      ushort4 o;
      o.x = f2bf(Sf[(i+0)*132 + j]*inv);
      o.y = f2bf(Sf[(i+1)*132 + j]*inv);
      o.z = f2bf(Sf[(i+2)*132 + j]*inv);
      o.w = f2bf(Sf[(i+3)*132 + j]*inv);
      *(ushort4*)(kr + i) = o;
    }
  }
  __syncthreads();
  const int i0 = (tid>>4)*4, e0 = eb + (tid&15)*8;
  const u16* Yb = Y + (size_t)n*M3*HWN;
  float acc[4][8] = {};
  for(int j=0;j<128;j++){
    ushort4 av = *(const ushort4*)&k3T[(size_t)j*NSTR + i0];
    float a0 = bf2f(av.x), a1 = bf2f(av.y), a2 = bf2f(av.z), a3 = bf2f(av.w);
    const u16* vp = Yb + (size_t)(jb+j)*M3 + 512 + e0;
    uint4 U0 = *(const uint4*)vp;
    float bv[8];
    bf2x2(U0.x, bv[0], bv[1]);  bf2x2(U0.y, bv[2], bv[3]);
    bf2x2(U0.z, bv[4], bv[5]);  bf2x2(U0.w, bv[6], bv[7]);
    #pragma unroll
    for(int u=0;u<8;u++){
      acc[0][u] += a0*bv[u];
      acc[1][u] += a1*bv[u];
      acc[2][u] += a2*bv[u];
      acc[3][u] += a3*bv[u];
    }
  }
  float* pb = part + ((size_t)n*32 + kc)*LND*EDIM;
  #pragma unroll
  for(int s=0;s<4;s++)
    #pragma unroll
    for(int t=0;t<8;t+=4){
      float4 fv = make_float4(acc[s][t],acc[s][t+1],acc[s][t+2],acc[s][t+3]);
      *(float4*)&pb[(size_t)(i0+s)*EDIM + e0 + t] = fv;
    }
}

__global__ void k_fred(const float* __restrict__ part, float* __restrict__ B3){
  const int idx = blockIdx.x*256 + threadIdx.x;
  const int n = idx >> 14, rem = idx & 16383;
  const float* p = part + (size_t)n*32*16384 + rem;
  float s = 0.f;
  #pragma unroll
  for(int kc=0;kc<32;kc++) s += p[(size_t)kc*16384];
  B3[idx] = s;
}

// ---------------- C2[j][e] = sum_l Kinv[j][l]*B3[l][e] ----------------
__global__ __launch_bounds__(256) void k_c2(const float* __restrict__ KinvT, const float* __restrict__ B3,
                                            float* __restrict__ C2){
  const int eb = blockIdx.x*64, n = blockIdx.y, tid = threadIdx.x;
  __shared__ float KT[64][68];
  __shared__ float Bs2[64][68];
  {
    int l = tid>>2, o16 = (tid&3)*16;
    const float* kp = KinvT + (size_t)n*4096 + l*64 + o16;
    const float* bp = B3 + ((size_t)n*LND + l)*EDIM + eb + o16;
    #pragma unroll
    for(int t=0;t<16;t+=4){
      *(float4*)&KT[l][o16+t]  = *(const float4*)(kp+t);
      *(float4*)&Bs2[l][o16+t] = *(const float4*)(bp+t);
    }
  }
  __syncthreads();
  const int j0 = (tid>>4)*4, u0 = (tid&15)*4;
  float acc[4][4] = {};
  #pragma unroll 8
  for(int l=0;l<64;l++){
    f32x4 a = *(f32x4*)&KT[l][j0];
    f32x4 b = *(f32x4*)&Bs2[l][u0];
    #pragma unroll
    for(int s=0;s<4;s++)
      #pragma unroll
      for(int u=0;u<4;u++) acc[s][u] += a[s]*b[u];
  }
  #pragma unroll
  for(int s=0;s<4;s++){
    float4 fv = make_float4(acc[s][0],acc[s][1],acc[s][2],acc[s][3]);
    *(float4*)&C2[((size_t)n*LND + j0+s)*EDIM + eb + u0] = fv;
  }
}

// ---------------- out[i][e] = sum_j k1t[j][i]*C2[j][e] + v[i][e]; OM bf16 ----------------
__global__ __launch_bounds__(256) void k_out(const float* __restrict__ Z1, const float* __restrict__ C2,
                                             const u16* __restrict__ Y, u16* __restrict__ OM){
  const int ib = blockIdx.x*64, n = blockIdx.y, tid = threadIdx.x;
  __shared__ float K1s[64][68];
  __shared__ u16 C2s[64*264];
  {
    int j = tid>>2, i16 = (tid&3)*16;
    const float* zp = Z1 + ((size_t)n*LND + j)*HWN + ib + i16;
    #pragma unroll
    for(int t=0;t<16;t+=4) *(float4*)&K1s[j][i16+t] = *(const float4*)(zp+t);
    int e64 = (tid&3)*64;
    const float* cp = C2 + ((size_t)n*LND + j)*EDIM + e64;
    #pragma unroll
    for(int t=0;t<64;t+=4){
      float4 v = *(const float4*)(cp+t);
      C2s[j*264 + e64+t+0] = f2bf(v.x);
      C2s[j*264 + e64+t+1] = f2bf(v.y);
      C2s[j*264 + e64+t+2] = f2bf(v.z);
      C2s[j*264 + e64+t+3] = f2bf(v.w);
    }
  }
  __syncthreads();
  const int i0 = (tid>>4)*4, e0 = (tid&15)*16;
  float acc[4][16] = {};
  for(int j=0;j<64;j++){
    f32x4 a = *(f32x4*)&K1s[j][i0];
    const u16* cb = &C2s[j*264 + e0];
    uint4 U0 = *(const uint4*)cb;
    uint4 U1 = *(const uint4*)(cb+8);
    float bv[16];
    bf2x2(U0.x, bv[0], bv[1]);  bf2x2(U0.y, bv[2], bv[3]);
    bf2x2(U0.z, bv[4], bv[5]);  bf2x2(U0.w, bv[6], bv[7]);
    bf2x2(U1.x, bv[8], bv[9]);  bf2x2(U1.y, bv[10], bv[11]);
    bf2x2(U1.z, bv[12], bv[13]); bf2x2(U1.w, bv[14], bv[15]);
    #pragma unroll
    for(int u=0;u<16;u++){
      acc[0][u] += a[0]*bv[u];
      acc[1][u] += a[1]*bv[u];
      acc[2][u] += a[2]*bv[u];
      acc[3][u] += a[3]*bv[u];
    }
  }
  const u16* Yb = Y + (size_t)n*M3*HWN;
  u16* ob = OM + (size_t)n*HWN*EDIM;
  #pragma unroll
  for(int s=0;s<4;s++){
    int i = ib + i0 + s;
    const u16* vp = Yb + (size_t)i*M3 + 512 + e0;
    uint4 U0 = *(const uint4*)vp, U1 = *(const uint4*)(vp+8);
    float vv[16];
    bf2x2(U0.x, vv[0], vv[1]);  bf2x2(U0.y, vv[2], vv[3]);
    bf2x2(U0.z, vv[4], vv[5]);  bf2x2(U0.w, vv[6], vv[7]);
    bf2x2(U1.x, vv[8], vv[9]);  bf2x2(U1.y, vv[10], vv[11]);
    bf2x2(U1.z, vv[12], vv[13]); bf2x2(U1.w, vv[14], vv[15]);
    #pragma unroll
    for(int t=0;t<16;t+=4){
      ushort4 o;
      o.x = f2bf(acc[s][t+0]+vv[t+0]);
      o.y = f2bf(acc[s][t+1]+vv[t+1]);
      o.z = f2bf(acc[s][t+2]+vv[t+2]);
      o.w = f2bf(acc[s][t+3]+vv[t+3]);
      *(ushort4*)&ob[(size_t)i*EDIM + e0 + t] = o;
    }
  }
}

// ---------------- transpose of raw-reshaped OM ----------------
__global__ __launch_bounds__(256) void k_trans2(const u16* __restrict__ OM, u16* __restrict__ OMT){
  __shared__ u16 Ts[64*65];
  const int bi = blockIdx.x;
  const int n = bi>>8, rem = bi&255, et = rem>>6, pt = rem&63;
  const int e0 = et*64, p0 = pt*64, tid = threadIdx.x;
  const u16* omb = OM + (size_t)n*HWN*EDIM;
  {
    int ee = tid>>2, pj = (tid&3)*16;
    const u16* ip = omb + (size_t)(e0+ee)*HWN + p0 + pj;
    ushort4 v0 = *(const ushort4*)(ip);
    ushort4 v1 = *(const ushort4*)(ip+4);
    ushort4 v2 = *(const ushort4*)(ip+8);
    ushort4 v3 = *(const ushort4*)(ip+12);
    u16* tp = &Ts[ee*65 + pj];
    tp[0]=v0.x; tp[1]=v0.y; tp[2]=v0.z; tp[3]=v0.w;
    tp[4]=v1.x; tp[5]=v1.y; tp[6]=v1.z; tp[7]=v1.w;
    tp[8]=v2.x; tp[9]=v2.y; tp[10]=v2.z; tp[11]=v2.w;
    tp[12]=v3.x; tp[13]=v3.y; tp[14]=v3.z; tp[15]=v3.w;
  }
  __syncthreads();
  {
    int pp = tid>>2, ej = (tid&3)*16;
    u16* op = OMT + ((size_t)n*HWN + p0 + pp)*EDIM + e0 + ej;
    ushort4 o[4];
    #pragma unroll
    for(int j=0;j<16;j++) ((u16*)o)[j] = Ts[(ej+j)*65 + pp];
    *(ushort4*)(op+0)  = o[0];
    *(ushort4*)(op+4)  = o[1];
    *(ushort4*)(op+8)  = o[2];
    *(ushort4*)(op+12) = o[3];
  }
}

// ---------------- proj GEMM 128x128xK256 ----------------
__global__ __launch_bounds__(256) void k_proj(const float* __restrict__ w, const u16* __restrict__ OMT,
                                              const float* __restrict__ bias, float* __restrict__ out){
  __shared__ u16 As[128*KS2];
  __shared__ u16 Bs[128*KS2];
  const int bi = blockIdx.x;
  const int n = bi&7, rem = bi>>3;
  const int ch0 = (rem&1)*128, p0 = (rem>>1)*128;
  const int tid = threadIdx.x;
  const int c = tid&15, qq = (tid>>4)&3, w4 = tid>>6;
  const int wr0 = (w4&1)*64, wc0 = (w4>>1)*64;
  const u16* xb = OMT + ((size_t)n*HWN + p0)*EDIM;
  f32x4 acc[4][4];
  #pragma unroll
  for(int mt=0;mt<4;mt++)
    #pragma unroll
    for(int nt=0;nt<4;nt++){ acc[mt][nt][0]=0.f; acc[mt][nt][1]=0.f; acc[mt][nt][2]=0.f; acc[mt][nt][3]=0.f; }
  const int ra = tid&127, ca = tid>>7;
  for(int ph=0; ph<2; ph++){
    {
      const float* ga = w + (size_t)(ch0+ra)*EDIM + ph*128 + ca*64;
      u16* la = &As[ra*KS2 + ca*64];
      #pragma unroll
      for(int j=0;j<8;j++){
        float4 v0 = *(const float4*)(ga + j*8);
        float4 v1 = *(const float4*)(ga + j*8 + 4);
        ushort4 o0, o1;
        o0.x=f2bf(v0.x); o0.y=f2bf(v0.y); o0.z=f2bf(v0.z); o0.w=f2bf(v0.w);
        o1.x=f2bf(v1.x); o1.y=f2bf(v1.y); o1.z=f2bf(v1.z); o1.w=f2bf(v1.w);
        *(ushort4*)(la + j*8)     = o0;
        *(ushort4*)(la + j*8 + 4) = o1;
      }
    }
    {
      const u16* gb = xb + (size_t)ra*EDIM + ph*128 + ca*64;
      u16* lb = &Bs[ra*KS2 + ca*64];
      #pragma unroll
      for(int j=0;j<8;j++)
        *(short8*)(lb + j*8) = *(const short8*)(gb + j*8);
    }
    __syncthreads();
    #pragma unroll
    for(int kt=0;kt<4;kt++){
      short8 af[4], bf[4];
      #pragma unroll
      for(int mt=0;mt<4;mt++) af[mt] = *(const short8*)&As[(wr0+mt*16+c)*KS2 + kt*32 + qq*8];
      #pragma unroll
      for(int nt=0;nt<4;nt++) bf[nt] = *(const short8*)&Bs[(wc0+nt*16+c)*KS2 + kt*32 + qq*8];
      #pragma unroll
      for(int mt=0;mt<4;mt++)
        #pragma unroll
        for(int nt=0;nt<4;nt++)
          acc[mt][nt] = __builtin_amdgcn_mfma_f32_16x16x32_bf16(af[mt], bf[nt], acc[mt][nt], 0, 0, 0);
    }
    __syncthreads();
  }
  float* ob = out + (size_t)n*EDIM*HWN;
  #pragma unroll
  for(int mt=0;mt<4;mt++){
    int chb = ch0 + wr0 + mt*16 + 4*qq;
    float b0 = bias[chb], b1 = bias[chb+1], b2 = bias[chb+2], b3 = bias[chb+3];
    #pragma unroll
    for(int nt=0;nt<4;nt++){
      int p = p0 + wc0 + nt*16 + c;
      float* yp = ob + (size_t)chb*HWN + p;
      yp[0]             = acc[mt][nt][0]+b0;
      yp[HWN]           = acc[mt][nt][1]+b1;
      yp[2*(size_t)HWN] = acc[mt][nt][2]+b2;
      yp[3*(size_t)HWN] = acc[mt][nt][3]+b3;
    }
  }
}

extern "C" void kernel_launch(void* const* d_in, const int* in_sizes, int n_in,
                              void* d_out, int out_size, void* d_ws, size_t ws_size,
                              hipStream_t stream){
  (void)out_size; (void)ws_size;
  const float* x     = (const float*)d_in[0];
  const float* w_qkv = (const float*)d_in[1];
  const float* b_qkv = (const float*)d_in[2];
  const float* w_out = (const float*)d_in[3];
  const float* b_out = (const float*)d_in[4];
  for(int i=0;i<n_in;i++){
    switch(in_sizes[i]){
      case 8388608: x     = (const float*)d_in[i]; break;
      case 196608:  w_qkv = (const float*)d_in[i]; break;
      case 768:     b_qkv = (const float*)d_in[i]; break;
      case 65536:   w_out = (const float*)d_in[i]; break;
      case 256:     b_out = (const float*)d_in[i]; break;
      default: break;
    }
  }
  float* out = (float*)d_out;
  char* ws = (char*)d_ws;

  u16*   Y     = (u16*)(ws + 0);              // 50,331,648 B  bf16 [8][768*4096]
  float* qland = (float*)(ws + 50331648);
  float* kland = (float*)(ws + 50855936);
  float* Z1    = (float*)(ws + 51380224);
  float* Z3    = (float*)(ws + 59768832);
  float* KinvT = (float*)(ws + 68157440);
  u16*   Xt    = (u16*)(ws + 68288512);       // 16 MB region: Xt -> part -> OMT
  float* part  = (float*)(ws + 68288512);
  u16*   OMT   = (u16*)(ws + 68288512);
  float* B3    = (float*)(ws + 85065728);
  float* C2    = (float*)(ws + 85590016);
  u16*   OM    = (u16*)(ws + 86114304);       // 16 MB bf16

  k_prep    <<<dim3(2048),   256, 0, stream>>>(x, Xt);
  k_qkv     <<<dim3(1536),   256, 0, stream>>>(w_qkv, Xt, b_qkv, Y);
  k_land    <<<dim3(64,8),   256, 0, stream>>>(Y, qland, kland);
  k_landgemm<<<dim3(64,16),  256, 0, stream>>>(Y, qland, kland, Z1, Z3);
  k_soft1   <<<dim3(512),    256, 0, stream>>>(Z1);
  k_ns      <<<dim3(8),      256, 0, stream>>>(qland, kland, KinvT);
  k_f       <<<dim3(32,8,2), 256, 0, stream>>>(Z3, Y, part);
  k_fred    <<<dim3(512),    256, 0, stream>>>(part, B3);
  k_c2      <<<dim3(4,8),    256, 0, stream>>>(KinvT, B3, C2);
  k_out     <<<dim3(64,8),   256, 0, stream>>>(Z1, C2, Y, OM);
  k_trans2  <<<dim3(2048),   256, 0, stream>>>(OM, OMT);
  k_proj    <<<dim3(512),    256, 0, stream>>>(w_out, OMT, b_out, out);
}